// Round 1
// baseline (305367.896 us; speedup 1.0000x reference)
//
#include <hip/hip_runtime.h>

#define Bsz 128
#define Lseq 512
#define Hdim 256
#define Tn 16
#define START_TAG 14
#define END_TAG 15

typedef float f32x4 __attribute__((ext_vector_type(4)));
typedef short s16x8 __attribute__((ext_vector_type(8)));

__device__ __forceinline__ unsigned short f2bf(float f) {
    unsigned int u = __builtin_bit_cast(unsigned int, f);
    u += 0x7fffu + ((u >> 16) & 1u);          // RNE
    return (unsigned short)(u >> 16);
}
__device__ __forceinline__ float bf2f(unsigned int bits16) {
    return __builtin_bit_cast(float, bits16 << 16);
}
__device__ __forceinline__ float sigmoidf_(float x) {
    return 1.0f / (1.0f + __expf(-x));
}

// XCD-local (L2-scope) communication helpers.
// Groups are colocated on one XCD (role claimed by physical XCC_ID), so the
// per-XCD L2 is the coherence point: plain stores (L1 is write-through) +
// sc0 loads (bypass per-CU L1, return the L2 copy). No sc1 -> no L3 trip.
__device__ __forceinline__ void ldg_sc0_x8(const unsigned int* p, uint4& a, uint4& b) {
    asm volatile("global_load_dwordx4 %0, %2, off sc0\n\t"
                 "global_load_dwordx4 %1, %2, off offset:16 sc0\n\t"
                 "s_waitcnt vmcnt(0)"
                 : "=&v"(a), "=&v"(b) : "v"(p) : "memory");
}
__device__ __forceinline__ int ldg_sc0_i32(const int* p) {
    int v;
    asm volatile("global_load_dword %0, %1, off sc0\n\t"
                 "s_waitcnt vmcnt(0)"
                 : "=&v"(v) : "v"(p) : "memory");
    return v;
}

// emb fp32 [V*256] -> packed bf16 pairs [V*128]
__global__ void embprep_kernel(const float* __restrict__ emb,
                               unsigned int* __restrict__ embb, int n2) {
    int i = blockIdx.x * blockDim.x + threadIdx.x;
    int stride = gridDim.x * blockDim.x;
    for (; i < n2; i += stride)
        embb[i] = (unsigned int)f2bf(emb[2 * i]) | ((unsigned int)f2bf(emb[2 * i + 1]) << 16);
}

// wtile[dir][ug(16)][tl=gate(4)][ki(16)][lane(64)][4 uints] : MFMA B-frag order.
__global__ void wprep_kernel(const float* __restrict__ wih_f, const float* __restrict__ whh_f,
                             const float* __restrict__ wih_b, const float* __restrict__ whh_b,
                             unsigned int* __restrict__ wtile) {
    int bid = blockIdx.x;                 // ((dir*16+ug)*4+tl)*16+ki
    int ki  = bid & 15;
    int tl  = (bid >> 4) & 3;
    int ug  = (bid >> 6) & 15;
    int dir = bid >> 10;
    int t = threadIdx.x;                  // 256 = lane(64) x j(4)
    int lane = t >> 2, j = t & 3;
    int n = lane & 15, kq = lane >> 4;
    int k0 = ki * 32 + kq * 8 + 2 * j;
    int col = tl * 256 + ug * 16 + n;
    const float* wih = dir ? wih_b : wih_f;
    const float* whh = dir ? whh_b : whh_f;
    float f0, f1;
    if (k0 < 256) { f0 = wih[col * 256 + k0];       f1 = wih[col * 256 + k0 + 1]; }
    else          { f0 = whh[col * 256 + k0 - 256]; f1 = whh[col * 256 + k0 - 255]; }
    wtile[(size_t)bid * 256 + t] = (unsigned int)f2bf(f0) | ((unsigned int)f2bf(f1) << 16);
}

__global__ void lengths_kernel(const int* __restrict__ tag, int* __restrict__ lengths) {
    int b = blockIdx.x;
    int tid = threadIdx.x;
    int cnt = 0;
    for (int l = tid; l < Lseq; l += blockDim.x)
        cnt += (tag[b * Lseq + l] != 0) ? 1 : 0;
    for (int off = 32; off > 0; off >>= 1) cnt += __shfl_down(cnt, off);
    __shared__ int red[4];
    if ((tid & 63) == 0) red[tid >> 6] = cnt;
    __syncthreads();
    if (tid == 0) lengths[b] = red[0] + red[1] + red[2] + red[3];
}

// Persistent BiLSTM, 256 WGs (1/CU, enforced by LDS > 80 KiB). Role (dir,bg,ug)
// is claimed at runtime per physical XCD so each 16-WG sync group is fully
// XCD-colocated; the h ring + flags then live in that XCD's L2 (sc0 path).
__global__ __launch_bounds__(256, 1) void bilstm_persist(
    const int* __restrict__ bd,
    const unsigned int* __restrict__ embb,     // [V][128]
    const unsigned int* __restrict__ wtile,    // frag-ordered weights
    const float* __restrict__ b_f, const float* __restrict__ b_b,
    const float* __restrict__ w_cls,
    float* __restrict__ em_f, float* __restrict__ em_b,
    unsigned int* __restrict__ ring,           // [2 dir][2 par][128 b][128 uints]
    int* __restrict__ flags,                   // [512][16 grp][16 wg]
    int* __restrict__ xcd_ctr)                 // [8]
{
    const int tid = threadIdx.x;

    __shared__ unsigned int w_lds[16384];      // [4 tl][16 ki][64 lane][4]
    __shared__ unsigned int h_lds[16 * 132 + 320]; // [16 m][132] + pad to force 1 WG/CU
    __shared__ float g_lds[4][16][17];
    __shared__ float part_lds[16][17];
    __shared__ float bias_lds[64];
    __shared__ float wcls_lds[256];
    __shared__ int role_sh;

    // ---- claim role on this physical XCD ----
    if (tid == 0) {
        unsigned int xcc;
        asm volatile("s_getreg_b32 %0, hwreg(HW_REG_XCC_ID)" : "=s"(xcc));
        xcc &= 7u;
        int slot = atomicAdd(&xcd_ctr[xcc], 1);   // device-scope claim
        role_sh = (int)(xcc * 32u) + slot;        // 32 WGs per XCD => 2 groups
    }
    __syncthreads();
    const int role = role_sh;
    const int grp = role >> 4;       // 0..15, all 16 members share one XCD
    const int ug  = role & 15;
    const int dir = grp >> 3;
    const int bg  = grp & 7;
    const int gb0 = bg * 16;

    // ---- one-time staging ----
    {
        const unsigned int* wsrc = wtile + ((size_t)(dir * 16 + ug) << 14);
        for (int i = 0; i < 16; ++i) {
            int idx = tid + 256 * i;
            uint4 v = *(const uint4*)(wsrc + (size_t)idx * 4);
            *(uint4*)&w_lds[idx * 4] = v;
        }
        if (tid < 64) {
            const float* bias = dir ? b_b : b_f;
            bias_lds[tid] = bias[(tid >> 4) * 256 + ug * 16 + (tid & 15)];
        }
        wcls_lds[tid] = w_cls[(size_t)ug * (2 * Hdim) + dir * Hdim + tid];
    }

    // identities
    const int wv = tid >> 6;        // wave = gate
    const int l  = tid & 63;
    const int n  = l & 15;          // col-in-tile / batch m for A
    const int kq = l >> 4;
    const int cb = tid >> 4, cu = tid & 15;            // cell: (batch, unit)
    const int em_m = tid >> 4, em_seg = tid & 15;      // emission partial
    float c_reg = 0.f;
    float* emout = dir ? em_b : em_f;
    const int* bd_row = bd + (size_t)(gb0 + n) * Lseq; // token row for A-frag rows

    unsigned int* rbase = ring + (size_t)dir * 2 * 16384;

    __syncthreads();   // w_lds/bias/wcls ready

    // ---- prologue: acc_x for s=0 ----
    f32x4 acc_x = {0.f, 0.f, 0.f, 0.f};
    {
        const int t0 = dir ? (Lseq - 1) : 0;
        int tok = bd_row[t0];
        const unsigned int* xsrc = embb + (size_t)tok * 128 + kq * 4;
        #pragma unroll
        for (int ki = 0; ki < 8; ++ki) {
            uint4 xv = *(const uint4*)(xsrc + ki * 16);
            s16x8 a = __builtin_bit_cast(s16x8, xv);
            s16x8 b = *(const s16x8*)&w_lds[((wv * 16 + ki) * 64 + l) * 4];
            acc_x = __builtin_amdgcn_mfma_f32_16x16x32_bf16(a, b, acc_x, 0, 0, 0);
        }
    }

    for (int s = 0; s < Lseq; ++s) {
        const unsigned int* hprev = rbase + ((s & 1) ^ 1) * 16384;
        unsigned int*       hcur  = rbase + (s & 1) * 16384;

        // ---- A: stage h_{s-1} (sc0 L2-scope loads -> LDS) ----
        {
            int m = tid >> 4, q0 = (tid & 15) * 8;
            const unsigned int* src = hprev + (gb0 + m) * 128 + q0;
            uint4 va, vb;
            ldg_sc0_x8(src, va, vb);
            *(uint4*)&h_lds[m * 132 + q0]     = va;
            *(uint4*)&h_lds[m * 132 + q0 + 4] = vb;
        }
        __syncthreads();

        // ---- B: emission partial (tag ug, h_{t_prev}) + 8 h-MFMAs ----
        if (s > 0) {
            const unsigned int* hr = &h_lds[em_m * 132 + em_seg * 8];
            const float* wc = &wcls_lds[em_seg * 16];
            float p = 0.f;
            #pragma unroll
            for (int j = 0; j < 8; ++j) {
                unsigned int v = hr[j];
                p += bf2f(v & 0xffffu) * wc[2 * j] + bf2f(v >> 16) * wc[2 * j + 1];
            }
            part_lds[em_m][em_seg] = p;
        }
        {
            f32x4 acc = acc_x;
            #pragma unroll
            for (int kih = 0; kih < 8; ++kih) {
                s16x8 a = *(const s16x8*)&h_lds[n * 132 + kih * 16 + kq * 4];
                s16x8 b = *(const s16x8*)&w_lds[(((wv * 16) + 8 + kih) * 64 + l) * 4];
                acc = __builtin_amdgcn_mfma_f32_16x16x32_bf16(a, b, acc, 0, 0, 0);
            }
            #pragma unroll
            for (int r = 0; r < 4; ++r)
                g_lds[wv][kq * 4 + r][n] = acc[r];
        }
        __syncthreads();

        // ---- C: cell update + packed h store (plain store -> XCD L2) ----
        {
            float gi = g_lds[0][cb][cu] + bias_lds[cu];
            float gf = g_lds[1][cb][cu] + bias_lds[16 + cu];
            float gg = g_lds[2][cb][cu] + bias_lds[32 + cu];
            float go = g_lds[3][cb][cu] + bias_lds[48 + cu];
            float cn = sigmoidf_(gf) * c_reg + sigmoidf_(gi) * tanhf(gg);
            c_reg = cn;
            float hn = sigmoidf_(go) * tanhf(cn);
            unsigned int hbits = (unsigned int)f2bf(hn);
            unsigned int other = (unsigned int)__shfl_down((int)hbits, 1);
            if ((cu & 1) == 0) {
                unsigned int pk = hbits | (other << 16);
                *(volatile unsigned int*)(hcur + (gb0 + cb) * 128 + ug * 8 + (cu >> 1)) = pk;
            }
        }
        if (s > 0 && tid < 16) {
            float ssum = 0.f;
            #pragma unroll
            for (int q = 0; q < 16; ++q) ssum += part_lds[tid][q];
            int t_prev = dir ? (Lseq - s) : (s - 1);
            emout[((size_t)(gb0 + tid) * Lseq + t_prev) * Tn + ug] = ssum;
        }
        __syncthreads();   // drains h stores (vmcnt(0) before s_barrier => in L2)

        // ---- D: arrive (plain store, visible in XCD L2) ----
        if (tid == 0)
            *(volatile int*)&flags[((size_t)s * 16 + grp) * 16 + ug] = 1;

        // ---- E: x-half MFMAs for s+1 (register frags; hidden in poll window) ----
        if (s + 1 < Lseq) {
            const int tn = dir ? (Lseq - 2 - s) : (s + 1);
            int tok = bd_row[tn];
            const unsigned int* xsrc = embb + (size_t)tok * 128 + kq * 4;
            f32x4 ax = {0.f, 0.f, 0.f, 0.f};
            #pragma unroll
            for (int ki = 0; ki < 8; ++ki) {
                uint4 xv = *(const uint4*)(xsrc + ki * 16);
                s16x8 a = __builtin_bit_cast(s16x8, xv);
                s16x8 b = *(const s16x8*)&w_lds[((wv * 16 + ki) * 64 + l) * 4];
                ax = __builtin_amdgcn_mfma_f32_16x16x32_bf16(a, b, ax, 0, 0, 0);
            }
            acc_x = ax;
        }

        // ---- F: wave0 polls the 16 group flags via sc0 (one L2 line) ----
        if (wv == 0) {
            const int* flg = &flags[((size_t)s * 16 + grp) * 16];
            const int* ap = flg + (l & 15);
            while (true) {
                int v = ldg_sc0_i32(ap);
                if (__all(v != 0)) break;
                __builtin_amdgcn_s_sleep(1);
            }
        }
        __syncthreads();
    }

    // ---- tail: emission for the last timestep's h ----
    {
        const unsigned int* hlast = rbase + ((Lseq - 1) & 1) * 16384;
        int m = tid >> 4, q0 = (tid & 15) * 8;
        const unsigned int* src = hlast + (gb0 + m) * 128 + q0;
        uint4 va, vb;
        ldg_sc0_x8(src, va, vb);
        *(uint4*)&h_lds[m * 132 + q0]     = va;
        *(uint4*)&h_lds[m * 132 + q0 + 4] = vb;
        __syncthreads();
        {
            const unsigned int* hr = &h_lds[em_m * 132 + em_seg * 8];
            const float* wc = &wcls_lds[em_seg * 16];
            float p = 0.f;
            #pragma unroll
            for (int j = 0; j < 8; ++j) {
                unsigned int vv = hr[j];
                p += bf2f(vv & 0xffffu) * wc[2 * j] + bf2f(vv >> 16) * wc[2 * j + 1];
            }
            part_lds[em_m][em_seg] = p;
        }
        __syncthreads();
        if (tid < 16) {
            float ssum = 0.f;
            #pragma unroll
            for (int q = 0; q < 16; ++q) ssum += part_lds[tid][q];
            int t_tail = dir ? 0 : (Lseq - 1);
            emout[((size_t)(gb0 + tid) * Lseq + t_tail) * Tn + ug] = ssum;
        }
    }
}

__global__ void golden_kernel(const int* __restrict__ tag,
                              const float* __restrict__ em_f,
                              const float* __restrict__ em_b,
                              const float* __restrict__ b_cls,
                              const float* __restrict__ trans,
                              float* __restrict__ golden)
{
    int b = blockIdx.x;
    int tid = threadIdx.x;
    float s = 0.f;
    for (int l = tid; l < Lseq; l += blockDim.x) {
        int tg = tag[b * Lseq + l];
        if (tg != 0) {
            int prev = (l == 0) ? START_TAG : tag[b * Lseq + l - 1];
            size_t e = ((size_t)b * Lseq + l) * Tn + tg;
            s += em_f[e] + em_b[e] + b_cls[tg] + trans[prev * Tn + tg];
        }
    }
    for (int off = 32; off > 0; off >>= 1) s += __shfl_down(s, off);
    __shared__ float red[4];
    if ((tid & 63) == 0) red[tid >> 6] = s;
    __syncthreads();
    if (tid == 0) atomicAdd(golden, red[0] + red[1] + red[2] + red[3]);
}

__global__ void crf_forward_kernel(const float* __restrict__ em_f,
                                   const float* __restrict__ em_b,
                                   const float* __restrict__ b_cls,
                                   const float* __restrict__ trans,
                                   const int* __restrict__ lengths,
                                   float* __restrict__ allpath)
{
    int b = blockIdx.x;
    int lane = threadIdx.x;
    int j = lane & 15;
    float tcol[16];
    #pragma unroll
    for (int i = 0; i < 16; ++i) tcol[i] = trans[i * Tn + j];
    float bc = b_cls[j];
    size_t e0 = ((size_t)b * Lseq) * Tn + j;
    float alpha = em_f[e0] + em_b[e0] + bc + tcol[START_TAG];
    int len = lengths[b];
    for (int t = 1; t < Lseq; ++t) {
        float av[16];
        float m = -1e30f;
        #pragma unroll
        for (int i = 0; i < 16; ++i) {
            av[i] = __shfl(alpha, i) + tcol[i];
            m = fmaxf(m, av[i]);
        }
        float sum = 0.f;
        #pragma unroll
        for (int i = 0; i < 16; ++i) sum += __expf(av[i] - m);
        size_t e = ((size_t)b * Lseq + t) * Tn + j;
        float nv = em_f[e] + em_b[e] + bc + m + __logf(sum);
        alpha = (t < len) ? nv : alpha;
    }
    if (lane == END_TAG) atomicAdd(allpath, alpha);
}

__global__ void finalize_kernel(const float* __restrict__ scal, float* __restrict__ out) {
    out[0] = (scal[1] - scal[0]) / (float)Bsz;
}

extern "C" void kernel_launch(void* const* d_in, const int* in_sizes, int n_in,
                              void* d_out, int out_size, void* d_ws, size_t ws_size,
                              hipStream_t stream)
{
    (void)in_sizes; (void)n_in; (void)out_size; (void)ws_size;
    const int*   bd     = (const int*)d_in[0];
    const int*   tag    = (const int*)d_in[1];
    const float* emb    = (const float*)d_in[2];
    const float* w_ih_f = (const float*)d_in[3];
    const float* w_hh_f = (const float*)d_in[4];
    const float* b_f    = (const float*)d_in[5];
    const float* w_ih_b = (const float*)d_in[6];
    const float* w_hh_b = (const float*)d_in[7];
    const float* b_b    = (const float*)d_in[8];
    const float* w_cls  = (const float*)d_in[9];
    const float* b_cls  = (const float*)d_in[10];
    const float* trans  = (const float*)d_in[11];
    float* out = (float*)d_out;

    float* ws = (float*)d_ws;
    float* em_f = ws;                                        // 1048576 f
    float* em_b = em_f + (size_t)Bsz * Lseq * Tn;            // 1048576 f
    unsigned int* ring = (unsigned int*)(em_b + (size_t)Bsz * Lseq * Tn);  // 65536 u
    float* scal = (float*)(ring + 65536);                    // 8 f
    int* flags = (int*)(scal + 8);                           // 512*16*16
    int* xcd_ctr = flags + (size_t)Lseq * 16 * 16;           // 8
    int* lengths = xcd_ctr + 8;                              // 128
    unsigned int* wtile = (unsigned int*)(lengths + 128);    // 2*16*4*16*256 = 524288
    unsigned int* embb = wtile + (size_t)524288;             // 30000*128

    // zero ring + scal + flags + xcd_ctr (contiguous)
    size_t zbytes = (65536 + 8 + (size_t)Lseq * 16 * 16 + 8) * 4;
    hipMemsetAsync(ring, 0, zbytes, stream);

    embprep_kernel<<<2048, 256, 0, stream>>>(emb, embb, 30000 * 128);
    wprep_kernel<<<2048, 256, 0, stream>>>(w_ih_f, w_hh_f, w_ih_b, w_hh_b, wtile);
    lengths_kernel<<<Bsz, 256, 0, stream>>>(tag, lengths);

    void* kargs[] = {
        (void*)&bd, (void*)&embb, (void*)&wtile,
        (void*)&b_f, (void*)&b_b, (void*)&w_cls,
        (void*)&em_f, (void*)&em_b,
        (void*)&ring, (void*)&flags, (void*)&xcd_ctr
    };
    hipLaunchCooperativeKernel((const void*)bilstm_persist,
                               dim3(256), dim3(256), kargs, 0, stream);

    golden_kernel<<<Bsz, 256, 0, stream>>>(tag, em_f, em_b, b_cls, trans, scal);
    crf_forward_kernel<<<Bsz, 64, 0, stream>>>(em_f, em_b, b_cls, trans, lengths, scal + 1);
    finalize_kernel<<<1, 1, 0, stream>>>(scal, out);
}

// Round 2
// 11520.010 us; speedup vs baseline: 26.5076x; 26.5076x over previous
//
#include <hip/hip_runtime.h>

#define Bsz 128
#define Lseq 512
#define Hdim 256
#define Tn 16
#define START_TAG 14
#define END_TAG 15

typedef float f32x4 __attribute__((ext_vector_type(4)));
typedef short s16x8 __attribute__((ext_vector_type(8)));

__device__ __forceinline__ unsigned short f2bf(float f) {
    unsigned int u = __builtin_bit_cast(unsigned int, f);
    u += 0x7fffu + ((u >> 16) & 1u);          // RNE
    return (unsigned short)(u >> 16);
}
__device__ __forceinline__ float sigmoidf_(float x) {
    return 1.0f / (1.0f + __expf(-x));
}

// emb fp32 [V*256] -> packed bf16 pairs [V*128]
__global__ void embprep_kernel(const float* __restrict__ emb,
                               unsigned int* __restrict__ embb, int n2) {
    int i = blockIdx.x * blockDim.x + threadIdx.x;
    int stride = gridDim.x * blockDim.x;
    for (; i < n2; i += stride)
        embb[i] = (unsigned int)f2bf(emb[2 * i]) | ((unsigned int)f2bf(emb[2 * i + 1]) << 16);
}

// wtile[dir][ug(16)][tl=gate(4)][ki(16)][lane(64)][4 uints] : MFMA B-frag order.
// lane l: n=l&15, kq=l>>4; uint j holds k-elems ki*32+kq*8+2j, +1 of col tl*256+ug*16+n.
__global__ void wprep_kernel(const float* __restrict__ wih_f, const float* __restrict__ whh_f,
                             const float* __restrict__ wih_b, const float* __restrict__ whh_b,
                             unsigned int* __restrict__ wtile) {
    int bid = blockIdx.x;                 // ((dir*16+ug)*4+tl)*16+ki
    int ki  = bid & 15;
    int tl  = (bid >> 4) & 3;
    int ug  = (bid >> 6) & 15;
    int dir = bid >> 10;
    int t = threadIdx.x;                  // 256 = lane(64) x j(4)
    int lane = t >> 2, j = t & 3;
    int n = lane & 15, kq = lane >> 4;
    int k0 = ki * 32 + kq * 8 + 2 * j;
    int col = tl * 256 + ug * 16 + n;
    const float* wih = dir ? wih_b : wih_f;
    const float* whh = dir ? whh_b : whh_f;
    float f0, f1;
    if (k0 < 256) { f0 = wih[col * 256 + k0];       f1 = wih[col * 256 + k0 + 1]; }
    else          { f0 = whh[col * 256 + k0 - 256]; f1 = whh[col * 256 + k0 - 255]; }
    wtile[(size_t)bid * 256 + t] = (unsigned int)f2bf(f0) | ((unsigned int)f2bf(f1) << 16);
}

// w_cls [T=16][2H=512] -> em B-frags: wclsb[dir][ki(8)][lane(64)][4 uints]
// col n = tag, k = dir*256 + (ki*32 + kq*8 + 2j)
__global__ void wclsprep_kernel(const float* __restrict__ w_cls,
                                unsigned int* __restrict__ wclsb) {
    int bid = blockIdx.x;                 // dir*8 + ki ; 16 blocks
    int ki  = bid & 7;
    int dir = bid >> 3;
    int t = threadIdx.x;                  // 256 = lane(64) x j(4)
    int lane = t >> 2, j = t & 3;
    int n = lane & 15, kq = lane >> 4;
    int k0 = ki * 32 + kq * 8 + 2 * j;    // 0..255
    float f0 = w_cls[n * 512 + dir * 256 + k0];
    float f1 = w_cls[n * 512 + dir * 256 + k0 + 1];
    wclsb[(size_t)bid * 256 + t] = (unsigned int)f2bf(f0) | ((unsigned int)f2bf(f1) << 16);
}

__global__ void lengths_kernel(const int* __restrict__ tag, int* __restrict__ lengths) {
    int b = blockIdx.x;
    int tid = threadIdx.x;
    int cnt = 0;
    for (int l = tid; l < Lseq; l += blockDim.x)
        cnt += (tag[b * Lseq + l] != 0) ? 1 : 0;
    for (int off = 32; off > 0; off >>= 1) cnt += __shfl_down(cnt, off);
    __shared__ int red[4];
    if ((tid & 63) == 0) red[tid >> 6] = cnt;
    __syncthreads();
    if (tid == 0) lengths[b] = red[0] + red[1] + red[2] + red[3];
}

// Self-contained BiLSTM: 16 WGs (2 dir x 8 batch-groups) x 512 threads.
// Each WG: 16 batches x ALL 256 units; h stays in LDS (no cross-WG traffic).
// Weights streamed from L2 each step as pre-formatted B-frags (1 MB/WG/step;
// 2 MB/XCD resident in 4 MB L2). Wave w owns unit-groups {2w, 2w+1}:
// 128 MFMAs/step into 8 independent acc chains; cell fully in registers.
// Emission piggybacks as 8 MFMAs on wave 0. One __syncthreads per step.
__global__ __launch_bounds__(512, 2) void bilstm16(
    const int* __restrict__ bd,
    const unsigned int* __restrict__ embb,     // [V][128]
    const unsigned int* __restrict__ wtile,    // frag-ordered weights
    const float* __restrict__ b_f, const float* __restrict__ b_b,
    const unsigned int* __restrict__ wclsb,    // em B-frags [2][8][256]
    float* __restrict__ em_f, float* __restrict__ em_b)
{
    const int bid = blockIdx.x;
    const int dir = bid >> 3;
    const int gb0 = (bid & 7) * 16;
    const int tid = threadIdx.x;
    const int wv  = tid >> 6;          // 0..7 : unit-groups {2wv, 2wv+1}
    const int l   = tid & 63;
    const int n   = l & 15;            // A-frag row = batch ; C col
    const int kq  = l >> 4;

    __shared__ unsigned int XH[2][16 * 132];   // x bf16 pairs, [m][132] (+4 pad)
    __shared__ unsigned int HHb[2][16 * 132];  // h bf16 pairs
    __shared__ unsigned int WCB[2048];         // em B-frags (this dir)
    __shared__ int tokL[2][16];

    // ---- init ----
    for (int i = tid; i < 16 * 132; i += 512) HHb[1][i] = 0;
    for (int i = tid; i < 2048; i += 512) WCB[i] = wclsb[(size_t)dir * 2048 + i];
    {
        int m = tid >> 5, q = tid & 31;
        int t0 = dir ? (Lseq - 1) : 0;
        int tok = bd[(size_t)(gb0 + m) * Lseq + t0];
        *(uint4*)&XH[0][m * 132 + q * 4] =
            *(const uint4*)(embb + (size_t)tok * 128 + q * 4);
    }
    if (tid < 16) {
        int t1 = dir ? (Lseq - 2) : 1;
        tokL[1][tid] = bd[(size_t)(gb0 + tid) * Lseq + t1];
    }
    float bias_v[2][4];
    {
        const float* bias = dir ? b_b : b_f;
        #pragma unroll
        for (int u01 = 0; u01 < 2; ++u01)
            #pragma unroll
            for (int tl = 0; tl < 4; ++tl)
                bias_v[u01][tl] = bias[tl * 256 + (2 * wv + u01) * 16 + n];
    }
    const unsigned int* wbase =
        wtile + ((size_t)(dir * 16 + 2 * wv) * 64) * 256 + l * 4;
    float* emout = dir ? em_b : em_f;

    f32x4 c0 = {0.f, 0.f, 0.f, 0.f};
    f32x4 c1 = {0.f, 0.f, 0.f, 0.f};

    __syncthreads();

    for (int s = 0; s < Lseq; ++s) {
        const int cur = s & 1;

        // ---- phase 0: issue prefetches (latency hidden under MFMAs) ----
        int tok2 = 0;
        const bool do_tok = (tid < 16) && (s + 2 < Lseq);
        if (do_tok) {
            int t2 = dir ? (Lseq - 3 - s) : (s + 2);
            tok2 = bd[(size_t)(gb0 + tid) * Lseq + t2];
        }
        uint4 xv = make_uint4(0, 0, 0, 0);
        const bool do_x = (s + 1 < Lseq);
        if (do_x) {
            int m = tid >> 5, q = tid & 31;
            int tok = tokL[cur ^ 1][m];
            xv = *(const uint4*)(embb + (size_t)tok * 128 + q * 4);
        }

        // ---- phase 1: h-half A-frags (h_{s-1}); emission piggyback ----
        s16x8 ah[8];
        #pragma unroll
        for (int ki = 0; ki < 8; ++ki)
            ah[ki] = *(const s16x8*)&HHb[cur ^ 1][n * 132 + ki * 16 + kq * 4];

        if (wv == 0 && s > 0) {
            f32x4 e = {0.f, 0.f, 0.f, 0.f};
            #pragma unroll
            for (int ki = 0; ki < 8; ++ki) {
                s16x8 wb = *(const s16x8*)&WCB[ki * 256 + l * 4];
                e = __builtin_amdgcn_mfma_f32_16x16x32_bf16(ah[ki], wb, e, 0, 0, 0);
            }
            int tp = dir ? (Lseq - s) : (s - 1);
            #pragma unroll
            for (int r = 0; r < 4; ++r)
                emout[((size_t)(gb0 + kq * 4 + r) * Lseq + tp) * Tn + n] = e[r];
        }

        // ---- phase 2: 128 MFMAs, B streamed from L2 (8 indep acc chains) ----
        f32x4 acc[2][4];
        #pragma unroll
        for (int u01 = 0; u01 < 2; ++u01)
            #pragma unroll
            for (int tl = 0; tl < 4; ++tl)
                acc[u01][tl] = (f32x4){0.f, 0.f, 0.f, 0.f};

        #pragma unroll
        for (int ki = 0; ki < 8; ++ki) {       // h-half: wtile ki = 8+ki
            #pragma unroll
            for (int u01 = 0; u01 < 2; ++u01)
                #pragma unroll
                for (int tl = 0; tl < 4; ++tl) {
                    s16x8 b = __builtin_bit_cast(s16x8,
                        *(const uint4*)(wbase + (size_t)(u01 * 64 + tl * 16 + 8 + ki) * 256));
                    acc[u01][tl] = __builtin_amdgcn_mfma_f32_16x16x32_bf16(
                        ah[ki], b, acc[u01][tl], 0, 0, 0);
                }
        }
        s16x8 ax[8];
        #pragma unroll
        for (int ki = 0; ki < 8; ++ki)
            ax[ki] = *(const s16x8*)&XH[cur][n * 132 + ki * 16 + kq * 4];
        #pragma unroll
        for (int ki = 0; ki < 8; ++ki) {       // x-half: wtile ki = ki
            #pragma unroll
            for (int u01 = 0; u01 < 2; ++u01)
                #pragma unroll
                for (int tl = 0; tl < 4; ++tl) {
                    s16x8 b = __builtin_bit_cast(s16x8,
                        *(const uint4*)(wbase + (size_t)(u01 * 64 + tl * 16 + ki) * 256));
                    acc[u01][tl] = __builtin_amdgcn_mfma_f32_16x16x32_bf16(
                        ax[ki], b, acc[u01][tl], 0, 0, 0);
                }
        }

        // ---- phase 3: cell in registers; pack h pairs -> LDS ----
        #pragma unroll
        for (int u01 = 0; u01 < 2; ++u01) {
            #pragma unroll
            for (int r = 0; r < 4; ++r) {
                float gi = acc[u01][0][r] + bias_v[u01][0];
                float gf = acc[u01][1][r] + bias_v[u01][1];
                float gg = acc[u01][2][r] + bias_v[u01][2];
                float go = acc[u01][3][r] + bias_v[u01][3];
                float cp = u01 ? c1[r] : c0[r];
                float cn = sigmoidf_(gf) * cp + sigmoidf_(gi) * tanhf(gg);
                if (u01) c1[r] = cn; else c0[r] = cn;
                float hn = sigmoidf_(go) * tanhf(cn);
                unsigned int hb = (unsigned int)f2bf(hn);
                unsigned int ot = (unsigned int)__shfl_down((int)hb, 1);
                if ((n & 1) == 0)
                    HHb[cur][(kq * 4 + r) * 132 + (2 * wv + u01) * 8 + (n >> 1)]
                        = hb | (ot << 16);
            }
        }

        // ---- phase 4: commit prefetches ----
        if (do_x) {
            int m = tid >> 5, q = tid & 31;
            *(uint4*)&XH[cur ^ 1][m * 132 + q * 4] = xv;
        }
        if (do_tok) tokL[cur][tid] = tok2;

        __syncthreads();
    }

    // ---- tail: emission for h_{L-1} ----
    if (wv == 0) {
        f32x4 e = {0.f, 0.f, 0.f, 0.f};
        #pragma unroll
        for (int ki = 0; ki < 8; ++ki) {
            s16x8 a = *(const s16x8*)&HHb[(Lseq - 1) & 1][n * 132 + ki * 16 + kq * 4];
            s16x8 wb = *(const s16x8*)&WCB[ki * 256 + l * 4];
            e = __builtin_amdgcn_mfma_f32_16x16x32_bf16(a, wb, e, 0, 0, 0);
        }
        int tp = dir ? 0 : (Lseq - 1);
        #pragma unroll
        for (int r = 0; r < 4; ++r)
            emout[((size_t)(gb0 + kq * 4 + r) * Lseq + tp) * Tn + n] = e[r];
    }
}

__global__ void golden_kernel(const int* __restrict__ tag,
                              const float* __restrict__ em_f,
                              const float* __restrict__ em_b,
                              const float* __restrict__ b_cls,
                              const float* __restrict__ trans,
                              float* __restrict__ golden)
{
    int b = blockIdx.x;
    int tid = threadIdx.x;
    float s = 0.f;
    for (int l = tid; l < Lseq; l += blockDim.x) {
        int tg = tag[b * Lseq + l];
        if (tg != 0) {
            int prev = (l == 0) ? START_TAG : tag[b * Lseq + l - 1];
            size_t e = ((size_t)b * Lseq + l) * Tn + tg;
            s += em_f[e] + em_b[e] + b_cls[tg] + trans[prev * Tn + tg];
        }
    }
    for (int off = 32; off > 0; off >>= 1) s += __shfl_down(s, off);
    __shared__ float red[4];
    if ((tid & 63) == 0) red[tid >> 6] = s;
    __syncthreads();
    if (tid == 0) atomicAdd(golden, red[0] + red[1] + red[2] + red[3]);
}

__global__ void crf_forward_kernel(const float* __restrict__ em_f,
                                   const float* __restrict__ em_b,
                                   const float* __restrict__ b_cls,
                                   const float* __restrict__ trans,
                                   const int* __restrict__ lengths,
                                   float* __restrict__ allpath)
{
    int b = blockIdx.x;
    int lane = threadIdx.x;
    int j = lane & 15;
    float tcol[16];
    #pragma unroll
    for (int i = 0; i < 16; ++i) tcol[i] = trans[i * Tn + j];
    float bc = b_cls[j];
    size_t e0 = ((size_t)b * Lseq) * Tn + j;
    float alpha = em_f[e0] + em_b[e0] + bc + tcol[START_TAG];
    int len = lengths[b];
    for (int t = 1; t < Lseq; ++t) {
        float av[16];
        float m = -1e30f;
        #pragma unroll
        for (int i = 0; i < 16; ++i) {
            av[i] = __shfl(alpha, i) + tcol[i];
            m = fmaxf(m, av[i]);
        }
        float sum = 0.f;
        #pragma unroll
        for (int i = 0; i < 16; ++i) sum += __expf(av[i] - m);
        size_t e = ((size_t)b * Lseq + t) * Tn + j;
        float nv = em_f[e] + em_b[e] + bc + m + __logf(sum);
        alpha = (t < len) ? nv : alpha;
    }
    if (lane == END_TAG) atomicAdd(allpath, alpha);
}

__global__ void finalize_kernel(const float* __restrict__ scal, float* __restrict__ out) {
    out[0] = (scal[1] - scal[0]) / (float)Bsz;
}

extern "C" void kernel_launch(void* const* d_in, const int* in_sizes, int n_in,
                              void* d_out, int out_size, void* d_ws, size_t ws_size,
                              hipStream_t stream)
{
    (void)in_sizes; (void)n_in; (void)out_size; (void)ws_size;
    const int*   bd     = (const int*)d_in[0];
    const int*   tag    = (const int*)d_in[1];
    const float* emb    = (const float*)d_in[2];
    const float* w_ih_f = (const float*)d_in[3];
    const float* w_hh_f = (const float*)d_in[4];
    const float* b_f    = (const float*)d_in[5];
    const float* w_ih_b = (const float*)d_in[6];
    const float* w_hh_b = (const float*)d_in[7];
    const float* b_b    = (const float*)d_in[8];
    const float* w_cls  = (const float*)d_in[9];
    const float* b_cls  = (const float*)d_in[10];
    const float* trans  = (const float*)d_in[11];
    float* out = (float*)d_out;

    float* ws = (float*)d_ws;
    float* em_f = ws;                                        // 1048576 f
    float* em_b = em_f + (size_t)Bsz * Lseq * Tn;            // 1048576 f
    float* scal = em_b + (size_t)Bsz * Lseq * Tn;            // 8 f
    int* lengths = (int*)(scal + 8);                         // 128 int
    unsigned int* wtile = (unsigned int*)(lengths + 128);    // 524288 u
    unsigned int* wclsb = wtile + (size_t)524288;            // 4096 u
    unsigned int* embb  = wclsb + 4096;                      // 3840000 u

    hipMemsetAsync(scal, 0, 8 * sizeof(float), stream);

    embprep_kernel<<<2048, 256, 0, stream>>>(emb, embb, 30000 * 128);
    wprep_kernel<<<2048, 256, 0, stream>>>(w_ih_f, w_hh_f, w_ih_b, w_hh_b, wtile);
    wclsprep_kernel<<<16, 256, 0, stream>>>(w_cls, wclsb);
    lengths_kernel<<<Bsz, 256, 0, stream>>>(tag, lengths);

    bilstm16<<<16, 512, 0, stream>>>(bd, embb, wtile, b_f, b_b, wclsb, em_f, em_b);

    golden_kernel<<<Bsz, 256, 0, stream>>>(tag, em_f, em_b, b_cls, trans, scal);
    crf_forward_kernel<<<Bsz, 64, 0, stream>>>(em_f, em_b, b_cls, trans, lengths, scal + 1);
    finalize_kernel<<<1, 1, 0, stream>>>(scal, out);
}

// Round 3
// 2748.715 us; speedup vs baseline: 111.0948x; 4.1911x over previous
//
#include <hip/hip_runtime.h>

#define Bsz 128
#define Lseq 512
#define Hdim 256
#define Tn 16
#define START_TAG 14
#define END_TAG 15

typedef float f32x4 __attribute__((ext_vector_type(4)));
typedef short s16x8 __attribute__((ext_vector_type(8)));

__device__ __forceinline__ unsigned short f2bf(float f) {
    unsigned int u = __builtin_bit_cast(unsigned int, f);
    u += 0x7fffu + ((u >> 16) & 1u);          // RNE
    return (unsigned short)(u >> 16);
}
__device__ __forceinline__ float bf2f(unsigned int bits16) {
    return __builtin_bit_cast(float, bits16 << 16);
}
__device__ __forceinline__ float sigmoidf_(float x) {
    return 1.0f / (1.0f + __expf(-x));
}

// emb fp32 [V*256] -> packed bf16 pairs [V*128]
__global__ void embprep_kernel(const float* __restrict__ emb,
                               unsigned int* __restrict__ embb, int n2) {
    int i = blockIdx.x * blockDim.x + threadIdx.x;
    int stride = gridDim.x * blockDim.x;
    for (; i < n2; i += stride)
        embb[i] = (unsigned int)f2bf(emb[2 * i]) | ((unsigned int)f2bf(emb[2 * i + 1]) << 16);
}

// wtile[dir][ug(16)][tl=gate(4)][ki(16)][lane(64)][4 uints] : MFMA B-frag order.
// lane l: n=l&15, kq=l>>4; uint j holds k-elems ki*32+kq*8+2j, +1 of col tl*256+ug*16+n.
__global__ void wprep_kernel(const float* __restrict__ wih_f, const float* __restrict__ whh_f,
                             const float* __restrict__ wih_b, const float* __restrict__ whh_b,
                             unsigned int* __restrict__ wtile) {
    int bid = blockIdx.x;                 // ((dir*16+ug)*4+tl)*16+ki
    int ki  = bid & 15;
    int tl  = (bid >> 4) & 3;
    int ug  = (bid >> 6) & 15;
    int dir = bid >> 10;
    int t = threadIdx.x;                  // 256 = lane(64) x j(4)
    int lane = t >> 2, j = t & 3;
    int n = lane & 15, kq = lane >> 4;
    int k0 = ki * 32 + kq * 8 + 2 * j;
    int col = tl * 256 + ug * 16 + n;
    const float* wih = dir ? wih_b : wih_f;
    const float* whh = dir ? whh_b : whh_f;
    float f0, f1;
    if (k0 < 256) { f0 = wih[col * 256 + k0];       f1 = wih[col * 256 + k0 + 1]; }
    else          { f0 = whh[col * 256 + k0 - 256]; f1 = whh[col * 256 + k0 - 255]; }
    wtile[(size_t)bid * 256 + t] = (unsigned int)f2bf(f0) | ((unsigned int)f2bf(f1) << 16);
}

__global__ void lengths_kernel(const int* __restrict__ tag, int* __restrict__ lengths) {
    int b = blockIdx.x;
    int tid = threadIdx.x;
    int cnt = 0;
    for (int l = tid; l < Lseq; l += blockDim.x)
        cnt += (tag[b * Lseq + l] != 0) ? 1 : 0;
    for (int off = 32; off > 0; off >>= 1) cnt += __shfl_down(cnt, off);
    __shared__ int red[4];
    if ((tid & 63) == 0) red[tid >> 6] = cnt;
    __syncthreads();
    if (tid == 0) lengths[b] = red[0] + red[1] + red[2] + red[3];
}

// Persistent BiLSTM, 256 WGs (1/CU). WG = dir(2) x bg(8: 16 batches) x ug(16: 16 units).
// Exchange h via TAGGED 64-bit relaxed agent-scope atomics: each ring word =
// (bf16 pair | (s+1)<<32), stored/loaded as one 8B single-copy atom. The tag
// travels with the data, so there is no flag publish, no release drain, and no
// post-poll reload: the poll IS the load. Safety by dataflow: a producer only
// reaches step s after tag-validating all of h_{s-1}, which proves every peer
// finished reading h_{s-2} from the parity slot being overwritten.
__global__ __launch_bounds__(256, 1) void bilstm_persist(
    const int* __restrict__ bd,
    const unsigned int* __restrict__ embb,         // [V][128]
    const unsigned int* __restrict__ wtile,        // frag-ordered weights
    const float* __restrict__ b_f, const float* __restrict__ b_b,
    const float* __restrict__ w_cls,
    float* __restrict__ em_f, float* __restrict__ em_b,
    unsigned long long* __restrict__ ring)         // [2 dir][2 par][128 b][128 words]
{
    const int wg  = blockIdx.x;
    const int dir = wg >> 7;
    const int bg  = (wg >> 4) & 7;
    const int ug  = wg & 15;
    const int tid = threadIdx.x;
    const int gb0 = bg * 16;

    __shared__ unsigned int w_lds[16384];      // [4 tl][16 ki][64 lane][4]
    __shared__ unsigned int h_lds[16 * 132];   // [16 m][128 uints + 4 pad]
    __shared__ float g_lds[4][16][17];
    __shared__ float part_lds[16][17];
    __shared__ float bias_lds[64];
    __shared__ float wcls_lds[256];

    // ---- one-time staging ----
    {
        const unsigned int* wsrc = wtile + ((size_t)(dir * 16 + ug) << 14);
        for (int i = 0; i < 16; ++i) {
            int idx = tid + 256 * i;
            uint4 v4 = *(const uint4*)(wsrc + (size_t)idx * 4);
            *(uint4*)&w_lds[idx * 4] = v4;
        }
        if (tid < 64) {
            const float* bias = dir ? b_b : b_f;
            bias_lds[tid] = bias[(tid >> 4) * 256 + ug * 16 + (tid & 15)];
        }
        wcls_lds[tid] = w_cls[(size_t)ug * (2 * Hdim) + dir * Hdim + tid];
        // h_{-1} = 0
        for (int i = tid; i < 16 * 132; i += 256) h_lds[i] = 0;
    }

    // identities
    const int wv = tid >> 6;        // wave = gate
    const int l  = tid & 63;
    const int n  = l & 15;          // col-in-tile / batch m for A
    const int kq = l >> 4;
    const int cb = tid >> 4, cu = tid & 15;            // cell: (batch, unit)
    const int em_m = tid >> 4, em_seg = tid & 15;      // emission partial
    const int hm = tid >> 4, hj0 = (tid & 15) * 8;     // ring load mapping
    float c_reg = 0.f;
    float* emout = dir ? em_b : em_f;
    const int* bd_row = bd + (size_t)(gb0 + n) * Lseq; // token row for A-frag rows

    unsigned long long* rbase = ring + (size_t)dir * 2 * 16384;

    __syncthreads();   // w_lds/bias/wcls/h_lds ready

    // ---- prologue: acc_x for s=0 ----
    f32x4 acc_x = {0.f, 0.f, 0.f, 0.f};
    {
        const int t0 = dir ? (Lseq - 1) : 0;
        int tok = bd_row[t0];
        const unsigned int* xsrc = embb + (size_t)tok * 128 + kq * 4;
        #pragma unroll
        for (int ki = 0; ki < 8; ++ki) {
            uint4 xv = *(const uint4*)(xsrc + ki * 16);
            s16x8 a = __builtin_bit_cast(s16x8, xv);
            s16x8 b = *(const s16x8*)&w_lds[((wv * 16 + ki) * 64 + l) * 4];
            acc_x = __builtin_amdgcn_mfma_f32_16x16x32_bf16(a, b, acc_x, 0, 0, 0);
        }
    }

    unsigned long long v[8];     // tag-validated h words carried across iters

    for (int s = 0; s < Lseq; ++s) {
        // ---- A: commit validated h_{s-1} words -> LDS ----
        if (s > 0) {
            #pragma unroll
            for (int j = 0; j < 8; ++j)
                h_lds[hm * 132 + hj0 + j] = (unsigned int)v[j];
        }
        __syncthreads();

        // ---- B: emission partial (tag ug, h_{t_prev}) + 8 h-MFMAs ----
        if (s > 0) {
            const unsigned int* hr = &h_lds[em_m * 132 + em_seg * 8];
            const float* wc = &wcls_lds[em_seg * 16];
            float p = 0.f;
            #pragma unroll
            for (int j = 0; j < 8; ++j) {
                unsigned int w = hr[j];
                p += bf2f(w & 0xffffu) * wc[2 * j] + bf2f(w >> 16) * wc[2 * j + 1];
            }
            part_lds[em_m][em_seg] = p;
        }
        {
            f32x4 acc = acc_x;
            #pragma unroll
            for (int kih = 0; kih < 8; ++kih) {
                s16x8 a = *(const s16x8*)&h_lds[n * 132 + kih * 16 + kq * 4];
                s16x8 b = *(const s16x8*)&w_lds[(((wv * 16) + 8 + kih) * 64 + l) * 4];
                acc = __builtin_amdgcn_mfma_f32_16x16x32_bf16(a, b, acc, 0, 0, 0);
            }
            #pragma unroll
            for (int r = 0; r < 4; ++r)
                g_lds[wv][kq * 4 + r][n] = acc[r];
        }
        __syncthreads();

        // ---- C: cell update + tagged 64b h store; emission final ----
        {
            float gi = g_lds[0][cb][cu] + bias_lds[cu];
            float gf = g_lds[1][cb][cu] + bias_lds[16 + cu];
            float gg = g_lds[2][cb][cu] + bias_lds[32 + cu];
            float go = g_lds[3][cb][cu] + bias_lds[48 + cu];
            float cn = sigmoidf_(gf) * c_reg + sigmoidf_(gi) * tanhf(gg);
            c_reg = cn;
            float hn = sigmoidf_(go) * tanhf(cn);
            unsigned int hbits = (unsigned int)f2bf(hn);
            unsigned int other = (unsigned int)__shfl_down((int)hbits, 1);
            if ((cu & 1) == 0) {
                unsigned long long pk = (unsigned long long)(hbits | (other << 16))
                                      | ((unsigned long long)(s + 1) << 32);
                __hip_atomic_store(
                    rbase + ((size_t)(s & 1) * 16384) + (size_t)(gb0 + cb) * 128 + ug * 8 + (cu >> 1),
                    pk, __ATOMIC_RELAXED, __HIP_MEMORY_SCOPE_AGENT);
            }
        }
        if (s > 0 && tid < 16) {
            float ssum = 0.f;
            #pragma unroll
            for (int q = 0; q < 16; ++q) ssum += part_lds[tid][q];
            int t_prev = dir ? (Lseq - s) : (s - 1);
            emout[((size_t)(gb0 + tid) * Lseq + t_prev) * Tn + ug] = ssum;
        }

        // ---- D: first-attempt loads of h_s (poll IS the load) ----
        const unsigned long long* src =
            rbase + ((size_t)(s & 1) * 16384) + (size_t)(gb0 + hm) * 128 + hj0;
        #pragma unroll
        for (int j = 0; j < 8; ++j)
            v[j] = __hip_atomic_load(src + j, __ATOMIC_RELAXED, __HIP_MEMORY_SCOPE_AGENT);

        // ---- E: x-half MFMAs for s+1 (hidden under the D round trip) ----
        if (s + 1 < Lseq) {
            const int tn = dir ? (Lseq - 2 - s) : (s + 1);
            int tok = bd_row[tn];
            const unsigned int* xsrc = embb + (size_t)tok * 128 + kq * 4;
            f32x4 ax = {0.f, 0.f, 0.f, 0.f};
            #pragma unroll
            for (int ki = 0; ki < 8; ++ki) {
                uint4 xv = *(const uint4*)(xsrc + ki * 16);
                s16x8 a = __builtin_bit_cast(s16x8, xv);
                s16x8 b = *(const s16x8*)&w_lds[((wv * 16 + ki) * 64 + l) * 4];
                ax = __builtin_amdgcn_mfma_f32_16x16x32_bf16(a, b, ax, 0, 0, 0);
            }
            acc_x = ax;
        }

        // ---- F: validate tags; retry only pending words ----
        {
            const unsigned long long want = (unsigned long long)(s + 1);
            unsigned int pend = 0xffu;
            while (true) {
                #pragma unroll
                for (int j = 0; j < 8; ++j)
                    if ((pend & (1u << j)) && ((v[j] >> 32) == want))
                        pend &= ~(1u << j);
                if (!pend) break;
                #pragma unroll
                for (int j = 0; j < 8; ++j)
                    if (pend & (1u << j))
                        v[j] = __hip_atomic_load(src + j, __ATOMIC_RELAXED,
                                                 __HIP_MEMORY_SCOPE_AGENT);
            }
        }
        // no barrier here: B(s)'s trailing barrier orders h_lds reuse at A(s+1)
    }

    // ---- tail: emission for h_{L-1} (v holds tag-512-validated words) ----
    {
        #pragma unroll
        for (int j = 0; j < 8; ++j)
            h_lds[hm * 132 + hj0 + j] = (unsigned int)v[j];
        __syncthreads();
        {
            const unsigned int* hr = &h_lds[em_m * 132 + em_seg * 8];
            const float* wc = &wcls_lds[em_seg * 16];
            float p = 0.f;
            #pragma unroll
            for (int j = 0; j < 8; ++j) {
                unsigned int vv = hr[j];
                p += bf2f(vv & 0xffffu) * wc[2 * j] + bf2f(vv >> 16) * wc[2 * j + 1];
            }
            part_lds[em_m][em_seg] = p;
        }
        __syncthreads();
        if (tid < 16) {
            float ssum = 0.f;
            #pragma unroll
            for (int q = 0; q < 16; ++q) ssum += part_lds[tid][q];
            int t_tail = dir ? 0 : (Lseq - 1);
            emout[((size_t)(gb0 + tid) * Lseq + t_tail) * Tn + ug] = ssum;
        }
    }
}

__global__ void golden_kernel(const int* __restrict__ tag,
                              const float* __restrict__ em_f,
                              const float* __restrict__ em_b,
                              const float* __restrict__ b_cls,
                              const float* __restrict__ trans,
                              float* __restrict__ golden)
{
    int b = blockIdx.x;
    int tid = threadIdx.x;
    float s = 0.f;
    for (int l = tid; l < Lseq; l += blockDim.x) {
        int tg = tag[b * Lseq + l];
        if (tg != 0) {
            int prev = (l == 0) ? START_TAG : tag[b * Lseq + l - 1];
            size_t e = ((size_t)b * Lseq + l) * Tn + tg;
            s += em_f[e] + em_b[e] + b_cls[tg] + trans[prev * Tn + tg];
        }
    }
    for (int off = 32; off > 0; off >>= 1) s += __shfl_down(s, off);
    __shared__ float red[4];
    if ((tid & 63) == 0) red[tid >> 6] = s;
    __syncthreads();
    if (tid == 0) atomicAdd(golden, red[0] + red[1] + red[2] + red[3]);
}

__global__ void crf_forward_kernel(const float* __restrict__ em_f,
                                   const float* __restrict__ em_b,
                                   const float* __restrict__ b_cls,
                                   const float* __restrict__ trans,
                                   const int* __restrict__ lengths,
                                   float* __restrict__ allpath)
{
    int b = blockIdx.x;
    int lane = threadIdx.x;
    int j = lane & 15;
    float tcol[16];
    #pragma unroll
    for (int i = 0; i < 16; ++i) tcol[i] = trans[i * Tn + j];
    float bc = b_cls[j];
    size_t e0 = ((size_t)b * Lseq) * Tn + j;
    float alpha = em_f[e0] + em_b[e0] + bc + tcol[START_TAG];
    int len = lengths[b];
    for (int t = 1; t < Lseq; ++t) {
        float av[16];
        float m = -1e30f;
        #pragma unroll
        for (int i = 0; i < 16; ++i) {
            av[i] = __shfl(alpha, i) + tcol[i];
            m = fmaxf(m, av[i]);
        }
        float sum = 0.f;
        #pragma unroll
        for (int i = 0; i < 16; ++i) sum += __expf(av[i] - m);
        size_t e = ((size_t)b * Lseq + t) * Tn + j;
        float nv = em_f[e] + em_b[e] + bc + m + __logf(sum);
        alpha = (t < len) ? nv : alpha;
    }
    if (lane == END_TAG) atomicAdd(allpath, alpha);
}

__global__ void finalize_kernel(const float* __restrict__ scal, float* __restrict__ out) {
    out[0] = (scal[1] - scal[0]) / (float)Bsz;
}

extern "C" void kernel_launch(void* const* d_in, const int* in_sizes, int n_in,
                              void* d_out, int out_size, void* d_ws, size_t ws_size,
                              hipStream_t stream)
{
    (void)in_sizes; (void)n_in; (void)out_size; (void)ws_size;
    const int*   bd     = (const int*)d_in[0];
    const int*   tag    = (const int*)d_in[1];
    const float* emb    = (const float*)d_in[2];
    const float* w_ih_f = (const float*)d_in[3];
    const float* w_hh_f = (const float*)d_in[4];
    const float* b_f    = (const float*)d_in[5];
    const float* w_ih_b = (const float*)d_in[6];
    const float* w_hh_b = (const float*)d_in[7];
    const float* b_b    = (const float*)d_in[8];
    const float* w_cls  = (const float*)d_in[9];
    const float* b_cls  = (const float*)d_in[10];
    const float* trans  = (const float*)d_in[11];
    float* out = (float*)d_out;

    float* ws = (float*)d_ws;
    float* em_f = ws;                                        // 1048576 f
    float* em_b = em_f + (size_t)Bsz * Lseq * Tn;            // 1048576 f
    unsigned long long* ring =
        (unsigned long long*)(em_b + (size_t)Bsz * Lseq * Tn);  // 65536 x 8B (8B-aligned)
    float* scal = (float*)(ring + 65536);                    // 8 f
    int* lengths = (int*)(scal + 8);                         // 128
    unsigned int* wtile = (unsigned int*)(lengths + 128);    // 524288 u
    unsigned int* embb = wtile + (size_t)524288;             // 3840000 u

    // zero ring (tag 0 = invalid; kills cross-launch tag aliasing) + scal
    hipMemsetAsync(ring, 0, 65536 * 8 + 8 * sizeof(float), stream);

    embprep_kernel<<<2048, 256, 0, stream>>>(emb, embb, 30000 * 128);
    wprep_kernel<<<2048, 256, 0, stream>>>(w_ih_f, w_hh_f, w_ih_b, w_hh_b, wtile);
    lengths_kernel<<<Bsz, 256, 0, stream>>>(tag, lengths);

    void* kargs[] = {
        (void*)&bd, (void*)&embb, (void*)&wtile,
        (void*)&b_f, (void*)&b_b, (void*)&w_cls,
        (void*)&em_f, (void*)&em_b,
        (void*)&ring
    };
    hipLaunchCooperativeKernel((const void*)bilstm_persist,
                               dim3(256), dim3(256), kargs, 0, stream);

    golden_kernel<<<Bsz, 256, 0, stream>>>(tag, em_f, em_b, b_cls, trans, scal);
    crf_forward_kernel<<<Bsz, 64, 0, stream>>>(em_f, em_b, b_cls, trans, lengths, scal + 1);
    finalize_kernel<<<1, 1, 0, stream>>>(scal, out);
}

// Round 5
// 2708.326 us; speedup vs baseline: 112.7515x; 1.0149x over previous
//
#include <hip/hip_runtime.h>

#define Bsz 128
#define Lseq 512
#define Hdim 256
#define Tn 16
#define START_TAG 14
#define END_TAG 15

typedef float f32x4 __attribute__((ext_vector_type(4)));
typedef short s16x8 __attribute__((ext_vector_type(8)));

__device__ __forceinline__ unsigned short f2bf(float f) {
    unsigned int u = __builtin_bit_cast(unsigned int, f);
    u += 0x7fffu + ((u >> 16) & 1u);          // RNE
    return (unsigned short)(u >> 16);
}
__device__ __forceinline__ float bf2f(unsigned int bits16) {
    return __builtin_bit_cast(float, bits16 << 16);
}
__device__ __forceinline__ float sigmoidf_(float x) {
    return 1.0f / (1.0f + __expf(-x));
}

// emb fp32 [V*256] -> packed bf16 pairs [V*128]
__global__ void embprep_kernel(const float* __restrict__ emb,
                               unsigned int* __restrict__ embb, int n2) {
    int i = blockIdx.x * blockDim.x + threadIdx.x;
    int stride = gridDim.x * blockDim.x;
    for (; i < n2; i += stride)
        embb[i] = (unsigned int)f2bf(emb[2 * i]) | ((unsigned int)f2bf(emb[2 * i + 1]) << 16);
}

// wtile[dir][ug(16)][tl=gate(4)][ki(16)][lane(64)][4 uints] : MFMA B-frag order.
// lane l: n=l&15, kq=l>>4; uint j holds k-elems ki*32+kq*8+2j, +1 of col tl*256+ug*16+n.
__global__ void wprep_kernel(const float* __restrict__ wih_f, const float* __restrict__ whh_f,
                             const float* __restrict__ wih_b, const float* __restrict__ whh_b,
                             unsigned int* __restrict__ wtile) {
    int bid = blockIdx.x;                 // ((dir*16+ug)*4+tl)*16+ki
    int ki  = bid & 15;
    int tl  = (bid >> 4) & 3;
    int ug  = (bid >> 6) & 15;
    int dir = bid >> 10;
    int t = threadIdx.x;                  // 256 = lane(64) x j(4)
    int lane = t >> 2, j = t & 3;
    int n = lane & 15, kq = lane >> 4;
    int k0 = ki * 32 + kq * 8 + 2 * j;
    int col = tl * 256 + ug * 16 + n;
    const float* wih = dir ? wih_b : wih_f;
    const float* whh = dir ? whh_b : whh_f;
    float f0, f1;
    if (k0 < 256) { f0 = wih[col * 256 + k0];       f1 = wih[col * 256 + k0 + 1]; }
    else          { f0 = whh[col * 256 + k0 - 256]; f1 = whh[col * 256 + k0 - 255]; }
    wtile[(size_t)bid * 256 + t] = (unsigned int)f2bf(f0) | ((unsigned int)f2bf(f1) << 16);
}

__global__ void lengths_kernel(const int* __restrict__ tag, int* __restrict__ lengths) {
    int b = blockIdx.x;
    int tid = threadIdx.x;
    int cnt = 0;
    for (int l = tid; l < Lseq; l += blockDim.x)
        cnt += (tag[b * Lseq + l] != 0) ? 1 : 0;
    for (int off = 32; off > 0; off >>= 1) cnt += __shfl_down(cnt, off);
    __shared__ int red[4];
    if ((tid & 63) == 0) red[tid >> 6] = cnt;
    __syncthreads();
    if (tid == 0) lengths[b] = red[0] + red[1] + red[2] + red[3];
}

// Persistent BiLSTM, 256 WGs (1/CU). WG = dir(2) x bg(8: 16 batches) x ug(16: 16 units).
// Per step: stage h -> 8 h-MFMAs -> cell -> [x-MFMAs overlap store flight] -> drain
// -> flag -> poll. The x-gather for s+1 is ISSUED at the top of step s (registers),
// so its HBM/L3 latency hides under phase A's ring-load wait instead of sitting
// serially between arrive and poll. Emission piggybacks on the staged h.
__global__ __launch_bounds__(256, 1) void bilstm_persist(
    const int* __restrict__ bd,
    const unsigned int* __restrict__ embb,     // [V][128]
    const unsigned int* __restrict__ wtile,    // frag-ordered weights
    const float* __restrict__ b_f, const float* __restrict__ b_b,
    const float* __restrict__ w_cls,
    float* __restrict__ em_f, float* __restrict__ em_b,
    unsigned int* __restrict__ ring,           // [2 dir][2 par][128 b][128 uints]
    int* __restrict__ flags)                   // [512][16 grp][16 wg]
{
    const int wg  = blockIdx.x;
    const int dir = wg >> 7;
    const int bg  = (wg >> 4) & 7;
    const int ug  = wg & 15;
    const int grp = dir * 8 + bg;
    const int tid = threadIdx.x;
    const int gb0 = bg * 16;

    __shared__ unsigned int w_lds[16384];      // [4 tl][16 ki][64 lane][4]
    __shared__ unsigned int h_lds[16 * 132];   // [16 m][128 uints + 4 pad]
    __shared__ float g_lds[4][16][17];
    __shared__ float part_lds[16][17];
    __shared__ float bias_lds[64];
    __shared__ float wcls_lds[256];

    // ---- one-time staging ----
    {
        const unsigned int* wsrc = wtile + ((size_t)(dir * 16 + ug) << 14);
        for (int i = 0; i < 16; ++i) {
            int idx = tid + 256 * i;
            uint4 v = *(const uint4*)(wsrc + (size_t)idx * 4);
            *(uint4*)&w_lds[idx * 4] = v;
        }
        if (tid < 64) {
            const float* bias = dir ? b_b : b_f;
            bias_lds[tid] = bias[(tid >> 4) * 256 + ug * 16 + (tid & 15)];
        }
        wcls_lds[tid] = w_cls[(size_t)ug * (2 * Hdim) + dir * Hdim + tid];
    }

    // identities
    const int wv = tid >> 6;        // wave = gate
    const int l  = tid & 63;
    const int n  = l & 15;          // col-in-tile / batch m for A
    const int kq = l >> 4;
    const int cb = tid >> 4, cu = tid & 15;            // cell: (batch, unit)
    const int em_m = tid >> 4, em_seg = tid & 15;      // emission partial
    float c_reg = 0.f;
    float* emout = dir ? em_b : em_f;
    const int* bd_row = bd + (size_t)(gb0 + n) * Lseq; // token row for A-frag rows

    unsigned int* rbase = ring + (size_t)dir * 2 * 16384;

    __syncthreads();   // w_lds/bias/wcls ready

    // ---- prologue: acc_x for s=0 (inline gather, one-time) ----
    f32x4 acc_x = {0.f, 0.f, 0.f, 0.f};
    {
        const int t0 = dir ? (Lseq - 1) : 0;
        int tok = bd_row[t0];
        const unsigned int* xsrc = embb + (size_t)tok * 128 + kq * 4;
        #pragma unroll
        for (int ki = 0; ki < 8; ++ki) {
            uint4 xv = *(const uint4*)(xsrc + ki * 16);
            s16x8 a = __builtin_bit_cast(s16x8, xv);
            s16x8 b = *(const s16x8*)&w_lds[((wv * 16 + ki) * 64 + l) * 4];
            acc_x = __builtin_amdgcn_mfma_f32_16x16x32_bf16(a, b, acc_x, 0, 0, 0);
        }
    }
    // token for step 1, pipelined one deep
    int tok_p1 = (Lseq > 1) ? bd_row[dir ? (Lseq - 2) : 1] : 0;

    for (int s = 0; s < Lseq; ++s) {
        const unsigned int* hprev = rbase + ((s & 1) ^ 1) * 16384;
        unsigned int*       hcur  = rbase + (s & 1) * 16384;

        // ---- P: issue x-gather for s+1 (flight overlaps phase A's wait) ----
        uint4 xg[8];
        const bool do_x = (s + 1 < Lseq);
        if (do_x) {
            const unsigned int* xsrc = embb + (size_t)tok_p1 * 128 + kq * 4;
            #pragma unroll
            for (int ki = 0; ki < 8; ++ki)
                xg[ki] = *(const uint4*)(xsrc + ki * 16);
        }
        if (s + 2 < Lseq)
            tok_p1 = bd_row[dir ? (Lseq - 3 - s) : (s + 2)];

        // ---- A: stage h_{s-1} (sc1 dword loads -> LDS) ----
        {
            int m = tid >> 4, q0 = (tid & 15) * 8;
            const unsigned int* src = hprev + (gb0 + m) * 128 + q0;
            unsigned int v[8];
            #pragma unroll
            for (int j = 0; j < 8; ++j)
                v[j] = __hip_atomic_load(src + j, __ATOMIC_RELAXED, __HIP_MEMORY_SCOPE_AGENT);
            *(uint4*)&h_lds[m * 132 + q0]     = make_uint4(v[0], v[1], v[2], v[3]);
            *(uint4*)&h_lds[m * 132 + q0 + 4] = make_uint4(v[4], v[5], v[6], v[7]);
        }
        __syncthreads();

        // ---- B: emission partial (tag ug, h_{t_prev}) + 8 h-MFMAs ----
        if (s > 0) {
            const unsigned int* hr = &h_lds[em_m * 132 + em_seg * 8];
            const float* wc = &wcls_lds[em_seg * 16];
            float p = 0.f;
            #pragma unroll
            for (int j = 0; j < 8; ++j) {
                unsigned int v = hr[j];
                p += bf2f(v & 0xffffu) * wc[2 * j] + bf2f(v >> 16) * wc[2 * j + 1];
            }
            part_lds[em_m][em_seg] = p;
        }
        {
            f32x4 acc = acc_x;
            #pragma unroll
            for (int kih = 0; kih < 8; ++kih) {
                s16x8 a = *(const s16x8*)&h_lds[n * 132 + kih * 16 + kq * 4];
                s16x8 b = *(const s16x8*)&w_lds[(((wv * 16) + 8 + kih) * 64 + l) * 4];
                acc = __builtin_amdgcn_mfma_f32_16x16x32_bf16(a, b, acc, 0, 0, 0);
            }
            #pragma unroll
            for (int r = 0; r < 4; ++r)
                g_lds[wv][kq * 4 + r][n] = acc[r];
        }
        __syncthreads();

        // ---- C: cell update + packed h store; emission final ----
        {
            float gi = g_lds[0][cb][cu] + bias_lds[cu];
            float gf = g_lds[1][cb][cu] + bias_lds[16 + cu];
            float gg = g_lds[2][cb][cu] + bias_lds[32 + cu];
            float go = g_lds[3][cb][cu] + bias_lds[48 + cu];
            float cn = sigmoidf_(gf) * c_reg + sigmoidf_(gi) * tanhf(gg);
            c_reg = cn;
            float hn = sigmoidf_(go) * tanhf(cn);
            unsigned int hbits = (unsigned int)f2bf(hn);
            unsigned int other = (unsigned int)__shfl_down((int)hbits, 1);
            if ((cu & 1) == 0) {
                unsigned int pk = hbits | (other << 16);
                __hip_atomic_store(hcur + (gb0 + cb) * 128 + ug * 8 + (cu >> 1), pk,
                                   __ATOMIC_RELAXED, __HIP_MEMORY_SCOPE_AGENT);
            }
        }
        if (s > 0 && tid < 16) {
            float ssum = 0.f;
            #pragma unroll
            for (int q = 0; q < 16; ++q) ssum += part_lds[tid][q];
            int t_prev = dir ? (Lseq - s) : (s - 1);
            emout[((size_t)(gb0 + tid) * Lseq + t_prev) * Tn + ug] = ssum;
        }

        // ---- E: x-half MFMAs for s+1 from registers (overlaps store flight) ----
        if (do_x) {
            f32x4 ax = {0.f, 0.f, 0.f, 0.f};
            #pragma unroll
            for (int ki = 0; ki < 8; ++ki) {
                s16x8 a = __builtin_bit_cast(s16x8, xg[ki]);
                s16x8 b = *(const s16x8*)&w_lds[((wv * 16 + ki) * 64 + l) * 4];
                ax = __builtin_amdgcn_mfma_f32_16x16x32_bf16(a, b, ax, 0, 0, 0);
            }
            acc_x = ax;
        }

        __syncthreads();   // drains h stores (vmcnt(0) before s_barrier)

        // ---- D: arrive ----
        if (tid == 0)
            __hip_atomic_store(&flags[((size_t)s * 16 + grp) * 16 + ug], 1,
                               __ATOMIC_RELAXED, __HIP_MEMORY_SCOPE_AGENT);

        // ---- F: wave0 polls the 16 group flags (one cache line) ----
        if (wv == 0) {
            const int* flg = &flags[((size_t)s * 16 + grp) * 16];
            while (true) {
                int v = (l < 16)
                    ? __hip_atomic_load(&flg[l], __ATOMIC_RELAXED, __HIP_MEMORY_SCOPE_AGENT)
                    : 1;
                if (__all(v != 0)) break;
                __builtin_amdgcn_s_sleep(1);
            }
        }
        __syncthreads();
    }

    // ---- tail: emission for the last timestep's h ----
    {
        const unsigned int* hlast = rbase + ((Lseq - 1) & 1) * 16384;
        int m = tid >> 4, q0 = (tid & 15) * 8;
        const unsigned int* src = hlast + (gb0 + m) * 128 + q0;
        unsigned int v[8];
        #pragma unroll
        for (int j = 0; j < 8; ++j)
            v[j] = __hip_atomic_load(src + j, __ATOMIC_RELAXED, __HIP_MEMORY_SCOPE_AGENT);
        *(uint4*)&h_lds[m * 132 + q0]     = make_uint4(v[0], v[1], v[2], v[3]);
        *(uint4*)&h_lds[m * 132 + q0 + 4] = make_uint4(v[4], v[5], v[6], v[7]);
        __syncthreads();
        {
            const unsigned int* hr = &h_lds[em_m * 132 + em_seg * 8];
            const float* wc = &wcls_lds[em_seg * 16];
            float p = 0.f;
            #pragma unroll
            for (int j = 0; j < 8; ++j) {
                unsigned int vv = hr[j];
                p += bf2f(vv & 0xffffu) * wc[2 * j] + bf2f(vv >> 16) * wc[2 * j + 1];
            }
            part_lds[em_m][em_seg] = p;
        }
        __syncthreads();
        if (tid < 16) {
            float ssum = 0.f;
            #pragma unroll
            for (int q = 0; q < 16; ++q) ssum += part_lds[tid][q];
            int t_tail = dir ? 0 : (Lseq - 1);
            emout[((size_t)(gb0 + tid) * Lseq + t_tail) * Tn + ug] = ssum;
        }
    }
}

__global__ void golden_kernel(const int* __restrict__ tag,
                              const float* __restrict__ em_f,
                              const float* __restrict__ em_b,
                              const float* __restrict__ b_cls,
                              const float* __restrict__ trans,
                              float* __restrict__ golden)
{
    int b = blockIdx.x;
    int tid = threadIdx.x;
    float s = 0.f;
    for (int l = tid; l < Lseq; l += blockDim.x) {
        int tg = tag[b * Lseq + l];
        if (tg != 0) {
            int prev = (l == 0) ? START_TAG : tag[b * Lseq + l - 1];
            size_t e = ((size_t)b * Lseq + l) * Tn + tg;
            s += em_f[e] + em_b[e] + b_cls[tg] + trans[prev * Tn + tg];
        }
    }
    for (int off = 32; off > 0; off >>= 1) s += __shfl_down(s, off);
    __shared__ float red[4];
    if ((tid & 63) == 0) red[tid >> 6] = s;
    __syncthreads();
    if (tid == 0) atomicAdd(golden, red[0] + red[1] + red[2] + red[3]);
}

__global__ void crf_forward_kernel(const float* __restrict__ em_f,
                                   const float* __restrict__ em_b,
                                   const float* __restrict__ b_cls,
                                   const float* __restrict__ trans,
                                   const int* __restrict__ lengths,
                                   float* __restrict__ allpath)
{
    int b = blockIdx.x;
    int lane = threadIdx.x;
    int j = lane & 15;
    float tcol[16];
    #pragma unroll
    for (int i = 0; i < 16; ++i) tcol[i] = trans[i * Tn + j];
    float bc = b_cls[j];
    size_t e0 = ((size_t)b * Lseq) * Tn + j;
    float alpha = em_f[e0] + em_b[e0] + bc + tcol[START_TAG];
    int len = lengths[b];
    for (int t = 1; t < Lseq; ++t) {
        float av[16];
        float m = -1e30f;
        #pragma unroll
        for (int i = 0; i < 16; ++i) {
            av[i] = __shfl(alpha, i) + tcol[i];
            m = fmaxf(m, av[i]);
        }
        float sum = 0.f;
        #pragma unroll
        for (int i = 0; i < 16; ++i) sum += __expf(av[i] - m);
        size_t e = ((size_t)b * Lseq + t) * Tn + j;
        float nv = em_f[e] + em_b[e] + bc + m + __logf(sum);
        alpha = (t < len) ? nv : alpha;
    }
    if (lane == END_TAG) atomicAdd(allpath, alpha);
}

__global__ void finalize_kernel(const float* __restrict__ scal, float* __restrict__ out) {
    out[0] = (scal[1] - scal[0]) / (float)Bsz;
}

extern "C" void kernel_launch(void* const* d_in, const int* in_sizes, int n_in,
                              void* d_out, int out_size, void* d_ws, size_t ws_size,
                              hipStream_t stream)
{
    (void)in_sizes; (void)n_in; (void)out_size; (void)ws_size;
    const int*   bd     = (const int*)d_in[0];
    const int*   tag    = (const int*)d_in[1];
    const float* emb    = (const float*)d_in[2];
    const float* w_ih_f = (const float*)d_in[3];
    const float* w_hh_f = (const float*)d_in[4];
    const float* b_f    = (const float*)d_in[5];
    const float* w_ih_b = (const float*)d_in[6];
    const float* w_hh_b = (const float*)d_in[7];
    const float* b_b    = (const float*)d_in[8];
    const float* w_cls  = (const float*)d_in[9];
    const float* b_cls  = (const float*)d_in[10];
    const float* trans  = (const float*)d_in[11];
    float* out = (float*)d_out;

    float* ws = (float*)d_ws;
    float* em_f = ws;                                        // 1048576 f
    float* em_b = em_f + (size_t)Bsz * Lseq * Tn;            // 1048576 f
    unsigned int* ring = (unsigned int*)(em_b + (size_t)Bsz * Lseq * Tn);  // 65536 u
    float* scal = (float*)(ring + 65536);                    // 8 f
    int* flags = (int*)(scal + 8);                           // 512*16*16
    int* lengths = flags + (size_t)Lseq * 16 * 16;           // 128
    unsigned int* wtile = (unsigned int*)(lengths + 128);    // 2*16*4*16*256 = 524288
    unsigned int* embb = wtile + (size_t)524288;             // 30000*128

    // zero ring + scal + flags (contiguous)
    size_t zbytes = (65536 + 8 + (size_t)Lseq * 16 * 16) * 4;
    hipMemsetAsync(ring, 0, zbytes, stream);

    embprep_kernel<<<2048, 256, 0, stream>>>(emb, embb, 30000 * 128);
    wprep_kernel<<<2048, 256, 0, stream>>>(w_ih_f, w_hh_f, w_ih_b, w_hh_b, wtile);
    lengths_kernel<<<Bsz, 256, 0, stream>>>(tag, lengths);

    void* kargs[] = {
        (void*)&bd, (void*)&embb, (void*)&wtile,
        (void*)&b_f, (void*)&b_b, (void*)&w_cls,
        (void*)&em_f, (void*)&em_b,
        (void*)&ring, (void*)&flags
    };
    hipLaunchCooperativeKernel((const void*)bilstm_persist,
                               dim3(256), dim3(256), kargs, 0, stream);

    golden_kernel<<<Bsz, 256, 0, stream>>>(tag, em_f, em_b, b_cls, trans, scal);
    crf_forward_kernel<<<Bsz, 64, 0, stream>>>(em_f, em_b, b_cls, trans, lengths, scal + 1);
    finalize_kernel<<<1, 1, 0, stream>>>(scal, out);
}

// Round 6
// 2441.190 us; speedup vs baseline: 125.0898x; 1.1094x over previous
//
#include <hip/hip_runtime.h>

#define Bsz 128
#define Lseq 512
#define Hdim 256
#define Tn 16
#define START_TAG 14
#define END_TAG 15

typedef float f32x4 __attribute__((ext_vector_type(4)));
typedef short s16x8 __attribute__((ext_vector_type(8)));

__device__ __forceinline__ unsigned short f2bf(float f) {
    unsigned int u = __builtin_bit_cast(unsigned int, f);
    u += 0x7fffu + ((u >> 16) & 1u);          // RNE
    return (unsigned short)(u >> 16);
}
__device__ __forceinline__ float bf2f(unsigned int bits16) {
    return __builtin_bit_cast(float, bits16 << 16);
}
__device__ __forceinline__ float sigmoidf_(float x) {
    return 1.0f / (1.0f + __expf(-x));
}

// emb fp32 [V*256] -> packed bf16 pairs [V*128]
__global__ void embprep_kernel(const float* __restrict__ emb,
                               unsigned int* __restrict__ embb, int n2) {
    int i = blockIdx.x * blockDim.x + threadIdx.x;
    int stride = gridDim.x * blockDim.x;
    for (; i < n2; i += stride)
        embb[i] = (unsigned int)f2bf(emb[2 * i]) | ((unsigned int)f2bf(emb[2 * i + 1]) << 16);
}

// wtile[dir][ug(16)][tl=gate(4)][ki(16)][lane(64)][4 uints] : MFMA B-frag order.
// lane l: n=l&15, kq=l>>4; uint j holds k-elems ki*32+kq*8+2j, +1 of col tl*256+ug*16+n.
__global__ void wprep_kernel(const float* __restrict__ wih_f, const float* __restrict__ whh_f,
                             const float* __restrict__ wih_b, const float* __restrict__ whh_b,
                             unsigned int* __restrict__ wtile) {
    int bid = blockIdx.x;                 // ((dir*16+ug)*4+tl)*16+ki
    int ki  = bid & 15;
    int tl  = (bid >> 4) & 3;
    int ug  = (bid >> 6) & 15;
    int dir = bid >> 10;
    int t = threadIdx.x;                  // 256 = lane(64) x j(4)
    int lane = t >> 2, j = t & 3;
    int n = lane & 15, kq = lane >> 4;
    int k0 = ki * 32 + kq * 8 + 2 * j;
    int col = tl * 256 + ug * 16 + n;
    const float* wih = dir ? wih_b : wih_f;
    const float* whh = dir ? whh_b : whh_f;
    float f0, f1;
    if (k0 < 256) { f0 = wih[col * 256 + k0];       f1 = wih[col * 256 + k0 + 1]; }
    else          { f0 = whh[col * 256 + k0 - 256]; f1 = whh[col * 256 + k0 - 255]; }
    wtile[(size_t)bid * 256 + t] = (unsigned int)f2bf(f0) | ((unsigned int)f2bf(f1) << 16);
}

__global__ void lengths_kernel(const int* __restrict__ tag, int* __restrict__ lengths) {
    int b = blockIdx.x;
    int tid = threadIdx.x;
    int cnt = 0;
    for (int l = tid; l < Lseq; l += blockDim.x)
        cnt += (tag[b * Lseq + l] != 0) ? 1 : 0;
    for (int off = 32; off > 0; off >>= 1) cnt += __shfl_down(cnt, off);
    __shared__ int red[4];
    if ((tid & 63) == 0) red[tid >> 6] = cnt;
    __syncthreads();
    if (tid == 0) lengths[b] = red[0] + red[1] + red[2] + red[3];
}

// Persistent BiLSTM, 256 WGs (1/CU). WG = dir(2) x bg(8: 16 batches) x ug(16: 16 units).
// Per-wave arrive / per-producer poll: consumer thread (m=tid>>4, q=tid&15)'s ring
// slice is produced entirely by WG q's wave (m>>2) = this thread's OWN wave index.
// Producer wave drains its own stores (s_waitcnt vmcnt(0)) and sets one flag
// flags[s][grp][wv][ug]; consumer polls exactly that flag then loads its slice.
// No full-WG drain barrier, no separate poll phase: 2 barriers/step total.
// x-half work for s+1 stays AFTER arrive (r5 lesson: earlier placement pollutes
// the staging vmcnt and delays the arrive).
__global__ __launch_bounds__(256, 1) void bilstm_persist(
    const int* __restrict__ bd,
    const unsigned int* __restrict__ embb,     // [V][128]
    const unsigned int* __restrict__ wtile,    // frag-ordered weights
    const float* __restrict__ b_f, const float* __restrict__ b_b,
    const float* __restrict__ w_cls,
    float* __restrict__ em_f, float* __restrict__ em_b,
    unsigned int* __restrict__ ring,           // [2 dir][2 par][128 b][128 uints]
    int* __restrict__ flags)                   // [512][16 grp][4 wv][16 ug]
{
    const int wg  = blockIdx.x;
    const int dir = wg >> 7;
    const int bg  = (wg >> 4) & 7;
    const int ug  = wg & 15;
    const int grp = dir * 8 + bg;
    const int tid = threadIdx.x;
    const int gb0 = bg * 16;

    __shared__ unsigned int w_lds[16384];      // [4 tl][16 ki][64 lane][4]
    __shared__ unsigned int h_lds[16 * 132];   // [16 m][128 uints + 4 pad]
    __shared__ float g_lds[4][16][17];
    __shared__ float part_lds[16][17];
    __shared__ float bias_lds[64];
    __shared__ float wcls_lds[256];

    // ---- one-time staging ----
    {
        const unsigned int* wsrc = wtile + ((size_t)(dir * 16 + ug) << 14);
        for (int i = 0; i < 16; ++i) {
            int idx = tid + 256 * i;
            uint4 v = *(const uint4*)(wsrc + (size_t)idx * 4);
            *(uint4*)&w_lds[idx * 4] = v;
        }
        if (tid < 64) {
            const float* bias = dir ? b_b : b_f;
            bias_lds[tid] = bias[(tid >> 4) * 256 + ug * 16 + (tid & 15)];
        }
        wcls_lds[tid] = w_cls[(size_t)ug * (2 * Hdim) + dir * Hdim + tid];
        for (int i = tid; i < 16 * 132; i += 256) h_lds[i] = 0;   // h_{-1} = 0
    }

    // identities
    const int wv = tid >> 6;        // wave = gate (B) = consumer slice's producer-wave
    const int l  = tid & 63;
    const int n  = l & 15;          // col-in-tile / batch m for A
    const int kq = l >> 4;
    const int cb = tid >> 4, cu = tid & 15;            // cell: (batch, unit)
    const int em_m = tid >> 4, em_seg = tid & 15;      // emission partial
    const int pm = tid >> 4, pq = tid & 15;            // staging: batch, producer ug
    float c_reg = 0.f;
    float* emout = dir ? em_b : em_f;
    const int* bd_row = bd + (size_t)(gb0 + n) * Lseq; // token row for A-frag rows

    unsigned int* rbase = ring + (size_t)dir * 2 * 16384;

    __syncthreads();   // w_lds/bias/wcls/h_lds ready

    // ---- prologue: acc_x for s=0 ----
    f32x4 acc_x = {0.f, 0.f, 0.f, 0.f};
    {
        const int t0 = dir ? (Lseq - 1) : 0;
        int tok = bd_row[t0];
        const unsigned int* xsrc = embb + (size_t)tok * 128 + kq * 4;
        #pragma unroll
        for (int ki = 0; ki < 8; ++ki) {
            uint4 xv = *(const uint4*)(xsrc + ki * 16);
            s16x8 a = __builtin_bit_cast(s16x8, xv);
            s16x8 b = *(const s16x8*)&w_lds[((wv * 16 + ki) * 64 + l) * 4];
            acc_x = __builtin_amdgcn_mfma_f32_16x16x32_bf16(a, b, acc_x, 0, 0, 0);
        }
    }

    for (int s = 0; s < Lseq; ++s) {
        unsigned int* hcur = rbase + (s & 1) * 16384;

        // ---- A': poll own producer-wave flag, then load own slice -> LDS ----
        if (s > 0) {
            const int* fp = &flags[((((size_t)(s - 1) * 16 + grp) * 4 + wv) << 4) + pq];
            while (__hip_atomic_load(fp, __ATOMIC_RELAXED, __HIP_MEMORY_SCOPE_AGENT) == 0)
                __builtin_amdgcn_s_sleep(1);
            const unsigned int* src = rbase + (((s - 1) & 1) ? 16384 : 0)
                                    + (gb0 + pm) * 128 + pq * 8;
            unsigned int v[8];
            #pragma unroll
            for (int j = 0; j < 8; ++j)
                v[j] = __hip_atomic_load(src + j, __ATOMIC_RELAXED, __HIP_MEMORY_SCOPE_AGENT);
            *(uint4*)&h_lds[pm * 132 + pq * 8]     = make_uint4(v[0], v[1], v[2], v[3]);
            *(uint4*)&h_lds[pm * 132 + pq * 8 + 4] = make_uint4(v[4], v[5], v[6], v[7]);
        }
        __syncthreads();   // bar1: h_lds(s-1) complete

        // ---- B: emission partial (tag ug, h_{t_prev}) + 8 h-MFMAs ----
        if (s > 0) {
            const unsigned int* hr = &h_lds[em_m * 132 + em_seg * 8];
            const float* wc = &wcls_lds[em_seg * 16];
            float p = 0.f;
            #pragma unroll
            for (int j = 0; j < 8; ++j) {
                unsigned int v = hr[j];
                p += bf2f(v & 0xffffu) * wc[2 * j] + bf2f(v >> 16) * wc[2 * j + 1];
            }
            part_lds[em_m][em_seg] = p;
        }
        {
            f32x4 acc = acc_x;
            #pragma unroll
            for (int kih = 0; kih < 8; ++kih) {
                s16x8 a = *(const s16x8*)&h_lds[n * 132 + kih * 16 + kq * 4];
                s16x8 b = *(const s16x8*)&w_lds[(((wv * 16) + 8 + kih) * 64 + l) * 4];
                acc = __builtin_amdgcn_mfma_f32_16x16x32_bf16(a, b, acc, 0, 0, 0);
            }
            #pragma unroll
            for (int r = 0; r < 4; ++r)
                g_lds[wv][kq * 4 + r][n] = acc[r];
        }
        __syncthreads();   // bar2: g_lds/part_lds complete

        // ---- C: cell update + packed h store; emission final; per-wave arrive ----
        {
            float gi = g_lds[0][cb][cu] + bias_lds[cu];
            float gf = g_lds[1][cb][cu] + bias_lds[16 + cu];
            float gg = g_lds[2][cb][cu] + bias_lds[32 + cu];
            float go = g_lds[3][cb][cu] + bias_lds[48 + cu];
            float cn = sigmoidf_(gf) * c_reg + sigmoidf_(gi) * tanhf(gg);
            c_reg = cn;
            float hn = sigmoidf_(go) * tanhf(cn);
            unsigned int hbits = (unsigned int)f2bf(hn);
            unsigned int other = (unsigned int)__shfl_down((int)hbits, 1);
            if ((cu & 1) == 0) {
                unsigned int pk = hbits | (other << 16);
                __hip_atomic_store(hcur + (gb0 + cb) * 128 + ug * 8 + (cu >> 1), pk,
                                   __ATOMIC_RELAXED, __HIP_MEMORY_SCOPE_AGENT);
            }
        }
        if (s > 0 && tid < 16) {
            float ssum = 0.f;
            #pragma unroll
            for (int q = 0; q < 16; ++q) ssum += part_lds[tid][q];
            int t_prev = dir ? (Lseq - s) : (s - 1);
            emout[((size_t)(gb0 + tid) * Lseq + t_prev) * Tn + ug] = ssum;
        }
        // per-wave drain of own stores, then arrive (no whole-WG barrier)
        asm volatile("s_waitcnt vmcnt(0)" ::: "memory");
        if (l == 0)
            __hip_atomic_store(&flags[((((size_t)s * 16 + grp) * 4 + wv) << 4) + ug], 1,
                               __ATOMIC_RELAXED, __HIP_MEMORY_SCOPE_AGENT);

        // ---- E: x-half MFMAs for s+1 (register frags; hidden in poll window) ----
        if (s + 1 < Lseq) {
            const int tn = dir ? (Lseq - 2 - s) : (s + 1);
            int tok = bd_row[tn];
            const unsigned int* xsrc = embb + (size_t)tok * 128 + kq * 4;
            f32x4 ax = {0.f, 0.f, 0.f, 0.f};
            #pragma unroll
            for (int ki = 0; ki < 8; ++ki) {
                uint4 xv = *(const uint4*)(xsrc + ki * 16);
                s16x8 a = __builtin_bit_cast(s16x8, xv);
                s16x8 b = *(const s16x8*)&w_lds[((wv * 16 + ki) * 64 + l) * 4];
                ax = __builtin_amdgcn_mfma_f32_16x16x32_bf16(a, b, ax, 0, 0, 0);
            }
            acc_x = ax;
        }
        // loop to A' of s+1: poll flags[s], load slice, commit, bar1
    }

    // ---- tail: stage h_{L-1} (poll + load) and emit its timestep ----
    {
        const int* fp = &flags[((((size_t)(Lseq - 1) * 16 + grp) * 4 + wv) << 4) + pq];
        while (__hip_atomic_load(fp, __ATOMIC_RELAXED, __HIP_MEMORY_SCOPE_AGENT) == 0)
            __builtin_amdgcn_s_sleep(1);
        const unsigned int* src = rbase + (((Lseq - 1) & 1) ? 16384 : 0)
                                + (gb0 + pm) * 128 + pq * 8;
        unsigned int v[8];
        #pragma unroll
        for (int j = 0; j < 8; ++j)
            v[j] = __hip_atomic_load(src + j, __ATOMIC_RELAXED, __HIP_MEMORY_SCOPE_AGENT);
        *(uint4*)&h_lds[pm * 132 + pq * 8]     = make_uint4(v[0], v[1], v[2], v[3]);
        *(uint4*)&h_lds[pm * 132 + pq * 8 + 4] = make_uint4(v[4], v[5], v[6], v[7]);
        __syncthreads();
        {
            const unsigned int* hr = &h_lds[em_m * 132 + em_seg * 8];
            const float* wc = &wcls_lds[em_seg * 16];
            float p = 0.f;
            #pragma unroll
            for (int j = 0; j < 8; ++j) {
                unsigned int vv = hr[j];
                p += bf2f(vv & 0xffffu) * wc[2 * j] + bf2f(vv >> 16) * wc[2 * j + 1];
            }
            part_lds[em_m][em_seg] = p;
        }
        __syncthreads();
        if (tid < 16) {
            float ssum = 0.f;
            #pragma unroll
            for (int q = 0; q < 16; ++q) ssum += part_lds[tid][q];
            int t_tail = dir ? 0 : (Lseq - 1);
            emout[((size_t)(gb0 + tid) * Lseq + t_tail) * Tn + ug] = ssum;
        }
    }
}

__global__ void golden_kernel(const int* __restrict__ tag,
                              const float* __restrict__ em_f,
                              const float* __restrict__ em_b,
                              const float* __restrict__ b_cls,
                              const float* __restrict__ trans,
                              float* __restrict__ golden)
{
    int b = blockIdx.x;
    int tid = threadIdx.x;
    float s = 0.f;
    for (int l = tid; l < Lseq; l += blockDim.x) {
        int tg = tag[b * Lseq + l];
        if (tg != 0) {
            int prev = (l == 0) ? START_TAG : tag[b * Lseq + l - 1];
            size_t e = ((size_t)b * Lseq + l) * Tn + tg;
            s += em_f[e] + em_b[e] + b_cls[tg] + trans[prev * Tn + tg];
        }
    }
    for (int off = 32; off > 0; off >>= 1) s += __shfl_down(s, off);
    __shared__ float red[4];
    if ((tid & 63) == 0) red[tid >> 6] = s;
    __syncthreads();
    if (tid == 0) atomicAdd(golden, red[0] + red[1] + red[2] + red[3]);
}

__global__ void crf_forward_kernel(const float* __restrict__ em_f,
                                   const float* __restrict__ em_b,
                                   const float* __restrict__ b_cls,
                                   const float* __restrict__ trans,
                                   const int* __restrict__ lengths,
                                   float* __restrict__ allpath)
{
    int b = blockIdx.x;
    int lane = threadIdx.x;
    int j = lane & 15;
    float tcol[16];
    #pragma unroll
    for (int i = 0; i < 16; ++i) tcol[i] = trans[i * Tn + j];
    float bc = b_cls[j];
    size_t e0 = ((size_t)b * Lseq) * Tn + j;
    float alpha = em_f[e0] + em_b[e0] + bc + tcol[START_TAG];
    int len = lengths[b];
    for (int t = 1; t < Lseq; ++t) {
        float av[16];
        float m = -1e30f;
        #pragma unroll
        for (int i = 0; i < 16; ++i) {
            av[i] = __shfl(alpha, i) + tcol[i];
            m = fmaxf(m, av[i]);
        }
        float sum = 0.f;
        #pragma unroll
        for (int i = 0; i < 16; ++i) sum += __expf(av[i] - m);
        size_t e = ((size_t)b * Lseq + t) * Tn + j;
        float nv = em_f[e] + em_b[e] + bc + m + __logf(sum);
        alpha = (t < len) ? nv : alpha;
    }
    if (lane == END_TAG) atomicAdd(allpath, alpha);
}

__global__ void finalize_kernel(const float* __restrict__ scal, float* __restrict__ out) {
    out[0] = (scal[1] - scal[0]) / (float)Bsz;
}

extern "C" void kernel_launch(void* const* d_in, const int* in_sizes, int n_in,
                              void* d_out, int out_size, void* d_ws, size_t ws_size,
                              hipStream_t stream)
{
    (void)in_sizes; (void)n_in; (void)out_size; (void)ws_size;
    const int*   bd     = (const int*)d_in[0];
    const int*   tag    = (const int*)d_in[1];
    const float* emb    = (const float*)d_in[2];
    const float* w_ih_f = (const float*)d_in[3];
    const float* w_hh_f = (const float*)d_in[4];
    const float* b_f    = (const float*)d_in[5];
    const float* w_ih_b = (const float*)d_in[6];
    const float* w_hh_b = (const float*)d_in[7];
    const float* b_b    = (const float*)d_in[8];
    const float* w_cls  = (const float*)d_in[9];
    const float* b_cls  = (const float*)d_in[10];
    const float* trans  = (const float*)d_in[11];
    float* out = (float*)d_out;

    float* ws = (float*)d_ws;
    float* em_f = ws;                                        // 1048576 f
    float* em_b = em_f + (size_t)Bsz * Lseq * Tn;            // 1048576 f
    unsigned int* ring = (unsigned int*)(em_b + (size_t)Bsz * Lseq * Tn);  // 65536 u
    float* scal = (float*)(ring + 65536);                    // 8 f
    int* flags = (int*)(scal + 8);                           // 512*16*4*16 = 524288
    int* lengths = flags + (size_t)Lseq * 16 * 4 * 16;       // 128
    unsigned int* wtile = (unsigned int*)(lengths + 128);    // 2*16*4*16*256 = 524288
    unsigned int* embb = wtile + (size_t)524288;             // 30000*128

    // zero ring + scal + flags (contiguous)
    size_t zbytes = (65536 + 8 + (size_t)Lseq * 16 * 4 * 16) * 4;
    hipMemsetAsync(ring, 0, zbytes, stream);

    embprep_kernel<<<2048, 256, 0, stream>>>(emb, embb, 30000 * 128);
    wprep_kernel<<<2048, 256, 0, stream>>>(w_ih_f, w_hh_f, w_ih_b, w_hh_b, wtile);
    lengths_kernel<<<Bsz, 256, 0, stream>>>(tag, lengths);

    void* kargs[] = {
        (void*)&bd, (void*)&embb, (void*)&wtile,
        (void*)&b_f, (void*)&b_b, (void*)&w_cls,
        (void*)&em_f, (void*)&em_b,
        (void*)&ring, (void*)&flags
    };
    hipLaunchCooperativeKernel((const void*)bilstm_persist,
                               dim3(256), dim3(256), kargs, 0, stream);

    golden_kernel<<<Bsz, 256, 0, stream>>>(tag, em_f, em_b, b_cls, trans, scal);
    crf_forward_kernel<<<Bsz, 64, 0, stream>>>(em_f, em_b, b_cls, trans, lengths, scal + 1);
    finalize_kernel<<<1, 1, 0, stream>>>(scal, out);
}

// Round 7
// 2234.466 us; speedup vs baseline: 136.6626x; 1.0925x over previous
//
#include <hip/hip_runtime.h>

#define Bsz 128
#define Lseq 512
#define Hdim 256
#define Tn 16
#define START_TAG 14
#define END_TAG 15

typedef float f32x4 __attribute__((ext_vector_type(4)));
typedef short s16x8 __attribute__((ext_vector_type(8)));

__device__ __forceinline__ unsigned short f2bf(float f) {
    unsigned int u = __builtin_bit_cast(unsigned int, f);
    u += 0x7fffu + ((u >> 16) & 1u);          // RNE
    return (unsigned short)(u >> 16);
}
__device__ __forceinline__ float bf2f(unsigned int bits16) {
    return __builtin_bit_cast(float, bits16 << 16);
}
__device__ __forceinline__ float sigmoidf_(float x) {
    return 1.0f / (1.0f + __expf(-x));
}

// emb fp32 [V*256] -> packed bf16 pairs [V*128]
__global__ void embprep_kernel(const float* __restrict__ emb,
                               unsigned int* __restrict__ embb, int n2) {
    int i = blockIdx.x * blockDim.x + threadIdx.x;
    int stride = gridDim.x * blockDim.x;
    for (; i < n2; i += stride)
        embb[i] = (unsigned int)f2bf(emb[2 * i]) | ((unsigned int)f2bf(emb[2 * i + 1]) << 16);
}

// wtile[dir][ug(16)][tl=gate(4)][ki(16)][lane(64)][4 uints] : MFMA B-frag order.
// lane l: n=l&15, kq=l>>4; uint j holds k-elems ki*32+kq*8+2j, +1 of col tl*256+ug*16+n.
__global__ void wprep_kernel(const float* __restrict__ wih_f, const float* __restrict__ whh_f,
                             const float* __restrict__ wih_b, const float* __restrict__ whh_b,
                             unsigned int* __restrict__ wtile) {
    int bid = blockIdx.x;                 // ((dir*16+ug)*4+tl)*16+ki
    int ki  = bid & 15;
    int tl  = (bid >> 4) & 3;
    int ug  = (bid >> 6) & 15;
    int dir = bid >> 10;
    int t = threadIdx.x;                  // 256 = lane(64) x j(4)
    int lane = t >> 2, j = t & 3;
    int n = lane & 15, kq = lane >> 4;
    int k0 = ki * 32 + kq * 8 + 2 * j;
    int col = tl * 256 + ug * 16 + n;
    const float* wih = dir ? wih_b : wih_f;
    const float* whh = dir ? whh_b : whh_f;
    float f0, f1;
    if (k0 < 256) { f0 = wih[col * 256 + k0];       f1 = wih[col * 256 + k0 + 1]; }
    else          { f0 = whh[col * 256 + k0 - 256]; f1 = whh[col * 256 + k0 - 255]; }
    wtile[(size_t)bid * 256 + t] = (unsigned int)f2bf(f0) | ((unsigned int)f2bf(f1) << 16);
}

__global__ void lengths_kernel(const int* __restrict__ tag, int* __restrict__ lengths) {
    int b = blockIdx.x;
    int tid = threadIdx.x;
    int cnt = 0;
    for (int l = tid; l < Lseq; l += blockDim.x)
        cnt += (tag[b * Lseq + l] != 0) ? 1 : 0;
    for (int off = 32; off > 0; off >>= 1) cnt += __shfl_down(cnt, off);
    __shared__ int red[4];
    if ((tid & 63) == 0) red[tid >> 6] = cnt;
    __syncthreads();
    if (tid == 0) lengths[b] = red[0] + red[1] + red[2] + red[3];
}

// Persistent BiLSTM, 256 WGs (1/CU). WG = dir(2) x bg(8: 16 batches) x ug(16: 16 units).
// Exchange h via TAGGED 64-bit relaxed agent-scope atomics: each ring word =
// (bf16 pair | (s+1)<<32); the tag travels with the data -> no drain, no flag,
// no separate poll trip (2 L3 trips/step vs r0's 3). Contention control (r3 fix):
// first-attempt load issued only AFTER the x-half MFMAs (peers' stores get ~2k cy
// of flight -> first probe mostly validates) and the retry loop backs off with
// s_sleep(2), reloading only pending words. Safety: a producer reaches step s
// only after tag-validating all of h_{s-1}, proving every peer finished reading
// h_{s-2} from the parity slot being overwritten.
__global__ __launch_bounds__(256, 1) void bilstm_persist(
    const int* __restrict__ bd,
    const unsigned int* __restrict__ embb,         // [V][128]
    const unsigned int* __restrict__ wtile,        // frag-ordered weights
    const float* __restrict__ b_f, const float* __restrict__ b_b,
    const float* __restrict__ w_cls,
    float* __restrict__ em_f, float* __restrict__ em_b,
    unsigned long long* __restrict__ ring)         // [2 dir][2 par][128 b][128 words]
{
    const int wg  = blockIdx.x;
    const int dir = wg >> 7;
    const int bg  = (wg >> 4) & 7;
    const int ug  = wg & 15;
    const int tid = threadIdx.x;
    const int gb0 = bg * 16;

    __shared__ unsigned int w_lds[16384];      // [4 tl][16 ki][64 lane][4]
    __shared__ unsigned int h_lds[16 * 132];   // [16 m][128 uints + 4 pad]
    __shared__ float g_lds[4][16][17];
    __shared__ float part_lds[16][17];
    __shared__ float bias_lds[64];
    __shared__ float wcls_lds[256];

    // ---- one-time staging ----
    {
        const unsigned int* wsrc = wtile + ((size_t)(dir * 16 + ug) << 14);
        for (int i = 0; i < 16; ++i) {
            int idx = tid + 256 * i;
            uint4 v4 = *(const uint4*)(wsrc + (size_t)idx * 4);
            *(uint4*)&w_lds[idx * 4] = v4;
        }
        if (tid < 64) {
            const float* bias = dir ? b_b : b_f;
            bias_lds[tid] = bias[(tid >> 4) * 256 + ug * 16 + (tid & 15)];
        }
        wcls_lds[tid] = w_cls[(size_t)ug * (2 * Hdim) + dir * Hdim + tid];
        // h_{-1} = 0
        for (int i = tid; i < 16 * 132; i += 256) h_lds[i] = 0;
    }

    // identities
    const int wv = tid >> 6;        // wave = gate
    const int l  = tid & 63;
    const int n  = l & 15;          // col-in-tile / batch m for A
    const int kq = l >> 4;
    const int cb = tid >> 4, cu = tid & 15;            // cell: (batch, unit)
    const int em_m = tid >> 4, em_seg = tid & 15;      // emission partial
    const int hm = tid >> 4, hj0 = (tid & 15) * 8;     // ring load mapping
    float c_reg = 0.f;
    float* emout = dir ? em_b : em_f;
    const int* bd_row = bd + (size_t)(gb0 + n) * Lseq; // token row for A-frag rows

    unsigned long long* rbase = ring + (size_t)dir * 2 * 16384;

    __syncthreads();   // w_lds/bias/wcls/h_lds ready

    // ---- prologue: acc_x for s=0 ----
    f32x4 acc_x = {0.f, 0.f, 0.f, 0.f};
    {
        const int t0 = dir ? (Lseq - 1) : 0;
        int tok = bd_row[t0];
        const unsigned int* xsrc = embb + (size_t)tok * 128 + kq * 4;
        #pragma unroll
        for (int ki = 0; ki < 8; ++ki) {
            uint4 xv = *(const uint4*)(xsrc + ki * 16);
            s16x8 a = __builtin_bit_cast(s16x8, xv);
            s16x8 b = *(const s16x8*)&w_lds[((wv * 16 + ki) * 64 + l) * 4];
            acc_x = __builtin_amdgcn_mfma_f32_16x16x32_bf16(a, b, acc_x, 0, 0, 0);
        }
    }
    // token for E(s=0) (gather target t=1), pipelined one step deep
    int tok_next = (Lseq > 1) ? bd_row[dir ? (Lseq - 2) : 1] : 0;

    unsigned long long v[8];     // tag-validated h words carried across iters

    for (int s = 0; s < Lseq; ++s) {
        // ---- A: commit validated h_{s-1} words -> LDS ----
        if (s > 0) {
            #pragma unroll
            for (int j = 0; j < 8; ++j)
                h_lds[hm * 132 + hj0 + j] = (unsigned int)v[j];
        }
        __syncthreads();

        // ---- B: emission partial (tag ug, h_{t_prev}) + 8 h-MFMAs ----
        if (s > 0) {
            const unsigned int* hr = &h_lds[em_m * 132 + em_seg * 8];
            const float* wc = &wcls_lds[em_seg * 16];
            float p = 0.f;
            #pragma unroll
            for (int j = 0; j < 8; ++j) {
                unsigned int w = hr[j];
                p += bf2f(w & 0xffffu) * wc[2 * j] + bf2f(w >> 16) * wc[2 * j + 1];
            }
            part_lds[em_m][em_seg] = p;
        }
        {
            f32x4 acc = acc_x;
            #pragma unroll
            for (int kih = 0; kih < 8; ++kih) {
                s16x8 a = *(const s16x8*)&h_lds[n * 132 + kih * 16 + kq * 4];
                s16x8 b = *(const s16x8*)&w_lds[(((wv * 16) + 8 + kih) * 64 + l) * 4];
                acc = __builtin_amdgcn_mfma_f32_16x16x32_bf16(a, b, acc, 0, 0, 0);
            }
            #pragma unroll
            for (int r = 0; r < 4; ++r)
                g_lds[wv][kq * 4 + r][n] = acc[r];
        }
        __syncthreads();

        // ---- C: cell update + tagged 64b h store; emission final ----
        {
            float gi = g_lds[0][cb][cu] + bias_lds[cu];
            float gf = g_lds[1][cb][cu] + bias_lds[16 + cu];
            float gg = g_lds[2][cb][cu] + bias_lds[32 + cu];
            float go = g_lds[3][cb][cu] + bias_lds[48 + cu];
            float cn = sigmoidf_(gf) * c_reg + sigmoidf_(gi) * tanhf(gg);
            c_reg = cn;
            float hn = sigmoidf_(go) * tanhf(cn);
            unsigned int hbits = (unsigned int)f2bf(hn);
            unsigned int other = (unsigned int)__shfl_down((int)hbits, 1);
            if ((cu & 1) == 0) {
                unsigned long long pk = (unsigned long long)(hbits | (other << 16))
                                      | ((unsigned long long)(s + 1) << 32);
                __hip_atomic_store(
                    rbase + ((size_t)(s & 1) * 16384) + (size_t)(gb0 + cb) * 128 + ug * 8 + (cu >> 1),
                    pk, __ATOMIC_RELAXED, __HIP_MEMORY_SCOPE_AGENT);
            }
        }
        if (s > 0 && tid < 16) {
            float ssum = 0.f;
            #pragma unroll
            for (int q = 0; q < 16; ++q) ssum += part_lds[tid][q];
            int t_prev = dir ? (Lseq - s) : (s - 1);
            emout[((size_t)(gb0 + tid) * Lseq + t_prev) * Tn + ug] = ssum;
        }

        // ---- E: x-half MFMAs for s+1 (tok pre-fetched; peers' stores in flight) ----
        if (s + 1 < Lseq) {
            const unsigned int* xsrc = embb + (size_t)tok_next * 128 + kq * 4;
            f32x4 ax = {0.f, 0.f, 0.f, 0.f};
            #pragma unroll
            for (int ki = 0; ki < 8; ++ki) {
                uint4 xv = *(const uint4*)(xsrc + ki * 16);
                s16x8 a = __builtin_bit_cast(s16x8, xv);
                s16x8 b = *(const s16x8*)&w_lds[((wv * 16 + ki) * 64 + l) * 4];
                ax = __builtin_amdgcn_mfma_f32_16x16x32_bf16(a, b, ax, 0, 0, 0);
            }
            acc_x = ax;
        }
        if (s + 2 < Lseq)
            tok_next = bd_row[dir ? (Lseq - 3 - s) : (s + 2)];   // consumed next step

        // ---- D: first-attempt loads of h_s (issued late: mostly validates) ----
        const unsigned long long* src =
            rbase + ((size_t)(s & 1) * 16384) + (size_t)(gb0 + hm) * 128 + hj0;
        #pragma unroll
        for (int j = 0; j < 8; ++j)
            v[j] = __hip_atomic_load(src + j, __ATOMIC_RELAXED, __HIP_MEMORY_SCOPE_AGENT);

        // ---- F: validate tags; retry only pending words with backoff ----
        {
            const unsigned long long want = (unsigned long long)(s + 1);
            unsigned int pend = 0xffu;
            while (true) {
                #pragma unroll
                for (int j = 0; j < 8; ++j)
                    if ((pend & (1u << j)) && ((v[j] >> 32) == want))
                        pend &= ~(1u << j);
                if (!pend) break;
                __builtin_amdgcn_s_sleep(2);
                #pragma unroll
                for (int j = 0; j < 8; ++j)
                    if (pend & (1u << j))
                        v[j] = __hip_atomic_load(src + j, __ATOMIC_RELAXED,
                                                 __HIP_MEMORY_SCOPE_AGENT);
            }
        }
        // no barrier here: B(s)'s trailing barrier orders h_lds reuse at A(s+1)
    }

    // ---- tail: emission for h_{L-1} (v holds tag-512-validated words) ----
    {
        #pragma unroll
        for (int j = 0; j < 8; ++j)
            h_lds[hm * 132 + hj0 + j] = (unsigned int)v[j];
        __syncthreads();
        {
            const unsigned int* hr = &h_lds[em_m * 132 + em_seg * 8];
            const float* wc = &wcls_lds[em_seg * 16];
            float p = 0.f;
            #pragma unroll
            for (int j = 0; j < 8; ++j) {
                unsigned int vv = hr[j];
                p += bf2f(vv & 0xffffu) * wc[2 * j] + bf2f(vv >> 16) * wc[2 * j + 1];
            }
            part_lds[em_m][em_seg] = p;
        }
        __syncthreads();
        if (tid < 16) {
            float ssum = 0.f;
            #pragma unroll
            for (int q = 0; q < 16; ++q) ssum += part_lds[tid][q];
            int t_tail = dir ? 0 : (Lseq - 1);
            emout[((size_t)(gb0 + tid) * Lseq + t_tail) * Tn + ug] = ssum;
        }
    }
}

__global__ void golden_kernel(const int* __restrict__ tag,
                              const float* __restrict__ em_f,
                              const float* __restrict__ em_b,
                              const float* __restrict__ b_cls,
                              const float* __restrict__ trans,
                              float* __restrict__ golden)
{
    int b = blockIdx.x;
    int tid = threadIdx.x;
    float s = 0.f;
    for (int l = tid; l < Lseq; l += blockDim.x) {
        int tg = tag[b * Lseq + l];
        if (tg != 0) {
            int prev = (l == 0) ? START_TAG : tag[b * Lseq + l - 1];
            size_t e = ((size_t)b * Lseq + l) * Tn + tg;
            s += em_f[e] + em_b[e] + b_cls[tg] + trans[prev * Tn + tg];
        }
    }
    for (int off = 32; off > 0; off >>= 1) s += __shfl_down(s, off);
    __shared__ float red[4];
    if ((tid & 63) == 0) red[tid >> 6] = s;
    __syncthreads();
    if (tid == 0) atomicAdd(golden, red[0] + red[1] + red[2] + red[3]);
}

__global__ void crf_forward_kernel(const float* __restrict__ em_f,
                                   const float* __restrict__ em_b,
                                   const float* __restrict__ b_cls,
                                   const float* __restrict__ trans,
                                   const int* __restrict__ lengths,
                                   float* __restrict__ allpath)
{
    int b = blockIdx.x;
    int lane = threadIdx.x;
    int j = lane & 15;
    float tcol[16];
    #pragma unroll
    for (int i = 0; i < 16; ++i) tcol[i] = trans[i * Tn + j];
    float bc = b_cls[j];
    size_t e0 = ((size_t)b * Lseq) * Tn + j;
    float alpha = em_f[e0] + em_b[e0] + bc + tcol[START_TAG];
    int len = lengths[b];
    for (int t = 1; t < Lseq; ++t) {
        float av[16];
        float m = -1e30f;
        #pragma unroll
        for (int i = 0; i < 16; ++i) {
            av[i] = __shfl(alpha, i) + tcol[i];
            m = fmaxf(m, av[i]);
        }
        float sum = 0.f;
        #pragma unroll
        for (int i = 0; i < 16; ++i) sum += __expf(av[i] - m);
        size_t e = ((size_t)b * Lseq + t) * Tn + j;
        float nv = em_f[e] + em_b[e] + bc + m + __logf(sum);
        alpha = (t < len) ? nv : alpha;
    }
    if (lane == END_TAG) atomicAdd(allpath, alpha);
}

__global__ void finalize_kernel(const float* __restrict__ scal, float* __restrict__ out) {
    out[0] = (scal[1] - scal[0]) / (float)Bsz;
}

extern "C" void kernel_launch(void* const* d_in, const int* in_sizes, int n_in,
                              void* d_out, int out_size, void* d_ws, size_t ws_size,
                              hipStream_t stream)
{
    (void)in_sizes; (void)n_in; (void)out_size; (void)ws_size;
    const int*   bd     = (const int*)d_in[0];
    const int*   tag    = (const int*)d_in[1];
    const float* emb    = (const float*)d_in[2];
    const float* w_ih_f = (const float*)d_in[3];
    const float* w_hh_f = (const float*)d_in[4];
    const float* b_f    = (const float*)d_in[5];
    const float* w_ih_b = (const float*)d_in[6];
    const float* w_hh_b = (const float*)d_in[7];
    const float* b_b    = (const float*)d_in[8];
    const float* w_cls  = (const float*)d_in[9];
    const float* b_cls  = (const float*)d_in[10];
    const float* trans  = (const float*)d_in[11];
    float* out = (float*)d_out;

    float* ws = (float*)d_ws;
    float* em_f = ws;                                        // 1048576 f
    float* em_b = em_f + (size_t)Bsz * Lseq * Tn;            // 1048576 f
    unsigned long long* ring =
        (unsigned long long*)(em_b + (size_t)Bsz * Lseq * Tn);  // 65536 x 8B (8B-aligned)
    float* scal = (float*)(ring + 65536);                    // 8 f
    int* lengths = (int*)(scal + 8);                         // 128
    unsigned int* wtile = (unsigned int*)(lengths + 128);    // 524288 u
    unsigned int* embb = wtile + (size_t)524288;             // 3840000 u

    // zero ring (tag 0 = invalid; kills cross-launch tag aliasing) + scal
    hipMemsetAsync(ring, 0, 65536 * 8 + 8 * sizeof(float), stream);

    embprep_kernel<<<2048, 256, 0, stream>>>(emb, embb, 30000 * 128);
    wprep_kernel<<<2048, 256, 0, stream>>>(w_ih_f, w_hh_f, w_ih_b, w_hh_b, wtile);
    lengths_kernel<<<Bsz, 256, 0, stream>>>(tag, lengths);

    void* kargs[] = {
        (void*)&bd, (void*)&embb, (void*)&wtile,
        (void*)&b_f, (void*)&b_b, (void*)&w_cls,
        (void*)&em_f, (void*)&em_b,
        (void*)&ring
    };
    hipLaunchCooperativeKernel((const void*)bilstm_persist,
                               dim3(256), dim3(256), kargs, 0, stream);

    golden_kernel<<<Bsz, 256, 0, stream>>>(tag, em_f, em_b, b_cls, trans, scal);
    crf_forward_kernel<<<Bsz, 64, 0, stream>>>(em_f, em_b, b_cls, trans, lengths, scal + 1);
    finalize_kernel<<<1, 1, 0, stream>>>(scal, out);
}